// Round 4
// baseline (845.988 us; speedup 1.0000x reference)
//
#include <hip/hip_runtime.h>

// GraphSAGE 3-layer forward. R4: bucketed 2-phase CSR build (kills place_k's
// 16x write amplification) + bf16 MFMA fused GEMMs + bf16 gather aggregation.
// Per layer: [A | Bt] = H @ [Ws|Wn] (one fused MFMA GEMM, A fp32+bias, Bt bf16)
//            Hnext = relu(A + mean_{e:dst=d} Bt[src[e]]) stored bf16
//            (layer2: no relu, fp32 straight to d_out)

#define NN 100000
#define NE 1600000
#define BSH 7               // 128 dst-nodes per bucket
#define BND 128
#define NB  782             // ceil(100000/128)

typedef __attribute__((ext_vector_type(8))) short short8;
typedef __attribute__((ext_vector_type(4))) float f32x4;
typedef unsigned int uint;
typedef unsigned short ushort;

__device__ inline ushort f2bf(float f) {
    uint u = __float_as_uint(f);
    u += 0x7FFFu + ((u >> 16) & 1u);
    return (ushort)(u >> 16);
}
__device__ inline float bf_lo(uint w) { return __uint_as_float(w << 16); }
__device__ inline float bf_hi(uint w) { return __uint_as_float(w & 0xFFFF0000u); }

// ---------------- bucketed CSR build ----------------
// Phase A: bucket histogram with LDS pre-aggregation (782 counters)
__global__ __launch_bounds__(256) void bucket_hist_k(const int* __restrict__ dst,
                                                     int* __restrict__ bcnt) {
    __shared__ int h[NB];
    const int t = threadIdx.x;
    for (int i = t; i < NB; i += 256) h[i] = 0;
    __syncthreads();
    const int stride = gridDim.x * 256;
    for (int e = blockIdx.x * 256 + t; e < NE; e += stride)
        atomicAdd(&h[dst[e] >> BSH], 1);
    __syncthreads();
    for (int i = t; i < NB; i += 256)
        if (h[i]) atomicAdd(&bcnt[i], h[i]);
}

// single-block exclusive scan of 782 bucket counts -> boff (and bwp copy)
__global__ __launch_bounds__(1024) void bscan_k(const int* __restrict__ bcnt,
                                                int* __restrict__ boff, int* __restrict__ bwp) {
    __shared__ int lds[1024];
    const int t = threadIdx.x;
    const int v = (t < NB) ? bcnt[t] : 0;
    lds[t] = v;
    __syncthreads();
    for (int off = 1; off < 1024; off <<= 1) {
        int nv = lds[t];
        if (t >= off) nv += lds[t - off];
        __syncthreads();
        lds[t] = nv;
        __syncthreads();
    }
    if (t < NB) {
        const int ex = lds[t] - v;
        boff[t] = ex;
        bwp[t] = ex;
    }
    if (t == 0) boff[NB] = NE;
}

// Phase B: scatter packed (src<<7 | dst&127) into per-bucket streams
__global__ __launch_bounds__(256) void pair_scatter_k(const int* __restrict__ src,
                                                      const int* __restrict__ dst,
                                                      int* __restrict__ bwp,
                                                      int* __restrict__ pb) {
    const int e = blockIdx.x * 256 + threadIdx.x;
    if (e >= NE) return;
    const int d = dst[e];
    const int pos = atomicAdd(&bwp[d >> BSH], 1);
    pb[pos] = (src[e] << BSH) | (d & (BND - 1));
}

// Phase C: one block per bucket — local count, scan, place esrc into the
// bucket's contiguous window (L2-resident), emit row[]
__global__ __launch_bounds__(256) void bucket_place_k(const int* __restrict__ boff,
                                                      const int* __restrict__ pb,
                                                      int* __restrict__ row,
                                                      int* __restrict__ esrc) {
    __shared__ int cnt[BND], wc[BND], excl[BND], scan[BND];
    const int b = blockIdx.x;
    const int t = threadIdx.x;
    if (t < BND) { cnt[t] = 0; wc[t] = 0; }
    __syncthreads();
    const int s0 = boff[b];
    const int s1 = boff[b + 1];
    for (int e = s0 + t; e < s1; e += 256)
        atomicAdd(&cnt[pb[e] & (BND - 1)], 1);
    __syncthreads();
    if (t < BND) scan[t] = cnt[t];
    __syncthreads();
    for (int off = 1; off < BND; off <<= 1) {
        int nv = 0;
        if (t < BND) {
            nv = scan[t];
            if (t >= off) nv += scan[t - off];
        }
        __syncthreads();
        if (t < BND) scan[t] = nv;
        __syncthreads();
    }
    if (t < BND) {
        const int ex = scan[t] - cnt[t];
        excl[t] = ex;
        const int node = b * BND + t;
        if (node <= NN) row[node] = s0 + ex;   // node==NN lands on row[NN]=NE
    }
    __syncthreads();
    for (int e = s0 + t; e < s1; e += 256) {
        const int p = pb[e];
        const int dl = p & (BND - 1);
        const int pos = s0 + excl[dl] + atomicAdd(&wc[dl], 1);
        esrc[pos] = p >> BSH;
    }
}

// ---------------- fp32 -> bf16 feature convert (x -> Hb) ----------------
__global__ __launch_bounds__(256) void cvt_x_k(const float* __restrict__ x, ushort* __restrict__ hb) {
    const int idx = blockIdx.x * 256 + threadIdx.x;
    if (idx >= NN * 16) return;
    const float4* xp = (const float4*)x;
    const float4 a = xp[idx * 2];
    const float4 b = xp[idx * 2 + 1];
    uint4 o;
    o.x = (uint)f2bf(a.x) | ((uint)f2bf(a.y) << 16);
    o.y = (uint)f2bf(a.z) | ((uint)f2bf(a.w) << 16);
    o.z = (uint)f2bf(b.x) | ((uint)f2bf(b.y) << 16);
    o.w = (uint)f2bf(b.z) | ((uint)f2bf(b.w) << 16);
    ((uint4*)hb)[idx] = o;
}

// ---------------- weight pack: [Ws|Wn] fp32 -> bf16 B-fragment-major ----------------
template<int NCS, int NCN>
__global__ __launch_bounds__(256) void pack_w_k(const float* __restrict__ ws, const float* __restrict__ wn,
                                                ushort* __restrict__ wf) {
    constexpr int TOTAL = ((NCS + NCN) / 16) * 4 * 64;
    const int idx = blockIdx.x * 256 + threadIdx.x;
    if (idx >= TOTAL) return;
    const int l = idx & 63;
    const int f = idx >> 6;
    const int kt = f & 3;
    const int ct = f >> 2;
    const int n = ct * 16 + (l & 15);
    const int k0 = kt * 32 + (l >> 4) * 8;
    uint w[4];
    #pragma unroll
    for (int p = 0; p < 4; ++p) {
        const int k = k0 + p * 2;
        float v0, v1;
        if (n < NCS) { v0 = ws[k * NCS + n];        v1 = ws[(k + 1) * NCS + n]; }
        else         { v0 = wn[k * NCN + (n - NCS)]; v1 = wn[(k + 1) * NCN + (n - NCS)]; }
        w[p] = (uint)f2bf(v0) | ((uint)f2bf(v1) << 16);
    }
    uint4 o; o.x = w[0]; o.y = w[1]; o.z = w[2]; o.w = w[3];
    ((uint4*)wf)[idx] = o;
}

// ---------------- fused MFMA GEMM: [A | Bt] = H @ Wcat ----------------
template<int NCS, int NCN>
__global__ __launch_bounds__(256) void gemm_mfma_k(
    const ushort* __restrict__ H, const ushort* __restrict__ Wf,
    const float* __restrict__ bias, float* __restrict__ A, ushort* __restrict__ Bt)
{
    constexpr int NCT = (NCS + NCN) / 16;
    const int g = (blockIdx.x * 256 + threadIdx.x) >> 6;
    if (g >= NN / 16) return;
    const int lane = threadIdx.x & 63;
    const int m = lane & 15;
    const int q = lane >> 4;

    const short8* hp = (const short8*)(H + (size_t)(g * 16 + m) * 128);
    short8 af[4];
    #pragma unroll
    for (int kt = 0; kt < 4; ++kt) af[kt] = hp[kt * 4 + q];

    f32x4 acc[NCT];
    #pragma unroll
    for (int i = 0; i < NCT; ++i) acc[i] = (f32x4){0.f, 0.f, 0.f, 0.f};

    const short8* wp = (const short8*)Wf;
    #pragma unroll
    for (int ct = 0; ct < NCT; ++ct) {
        #pragma unroll
        for (int kt = 0; kt < 4; ++kt) {
            const short8 bf = wp[(ct * 4 + kt) * 64 + lane];
            acc[ct] = __builtin_amdgcn_mfma_f32_16x16x32_bf16(af[kt], bf, acc[ct], 0, 0, 0);
        }
    }

    const int r0 = g * 16 + q * 4;
    #pragma unroll
    for (int ct = 0; ct < NCS / 16; ++ct) {
        const int c = ct * 16 + m;
        const float bv = bias[c];
        #pragma unroll
        for (int r = 0; r < 4; ++r)
            A[(size_t)(r0 + r) * NCS + c] = acc[ct][r] + bv;
    }
    #pragma unroll
    for (int ct = NCS / 16; ct < NCT; ++ct) {
        const int c = ct * 16 + m - NCS;
        #pragma unroll
        for (int r = 0; r < 4; ++r)
            Bt[(size_t)(r0 + r) * NCN + c] = f2bf(acc[ct][r]);
    }
}

// ---------------- aggregation ----------------
template<bool RELU>
__global__ __launch_bounds__(256) void agg128_k(
    const int* __restrict__ row, const int* __restrict__ esrc,
    const ushort* __restrict__ Bt, const float* __restrict__ A, ushort* __restrict__ Hb)
{
    const int node = (blockIdx.x * 256 + threadIdx.x) >> 6;
    if (node >= NN) return;
    const int lane = threadIdx.x & 63;
    const int e0 = row[node];
    const int e1 = row[node + 1];
    const uint* B32 = (const uint*)Bt;
    float a0 = 0.f, a1 = 0.f;
    int e = e0;
    for (; e + 4 <= e1; e += 4) {
        const int s0 = esrc[e], s1 = esrc[e + 1], s2 = esrc[e + 2], s3 = esrc[e + 3];
        const uint w0 = B32[(size_t)s0 * 64 + lane];
        const uint w1 = B32[(size_t)s1 * 64 + lane];
        const uint w2 = B32[(size_t)s2 * 64 + lane];
        const uint w3 = B32[(size_t)s3 * 64 + lane];
        a0 += (bf_lo(w0) + bf_lo(w1)) + (bf_lo(w2) + bf_lo(w3));
        a1 += (bf_hi(w0) + bf_hi(w1)) + (bf_hi(w2) + bf_hi(w3));
    }
    for (; e < e1; ++e) {
        const uint w = B32[(size_t)esrc[e] * 64 + lane];
        a0 += bf_lo(w);
        a1 += bf_hi(w);
    }
    const float invd = (e1 > e0) ? 1.0f / (float)(e1 - e0) : 0.0f;
    const float2 av = *(const float2*)(A + (size_t)node * 128 + lane * 2);
    float v0 = av.x + a0 * invd;
    float v1 = av.y + a1 * invd;
    if (RELU) { v0 = fmaxf(v0, 0.f); v1 = fmaxf(v1, 0.f); }
    ((uint*)Hb)[(size_t)node * 64 + lane] = (uint)f2bf(v0) | ((uint)f2bf(v1) << 16);
}

__global__ __launch_bounds__(256) void agg64_k(
    const int* __restrict__ row, const int* __restrict__ esrc,
    const ushort* __restrict__ Bt, float* __restrict__ out)
{
    const int node = (blockIdx.x * 256 + threadIdx.x) >> 6;
    if (node >= NN) return;
    const int lane = threadIdx.x & 63;
    const int e0 = row[node];
    const int e1 = row[node + 1];
    float a = 0.f;
    int e = e0;
    for (; e + 4 <= e1; e += 4) {
        const int s0 = esrc[e], s1 = esrc[e + 1], s2 = esrc[e + 2], s3 = esrc[e + 3];
        const float f0 = __uint_as_float((uint)Bt[(size_t)s0 * 64 + lane] << 16);
        const float f1 = __uint_as_float((uint)Bt[(size_t)s1 * 64 + lane] << 16);
        const float f2 = __uint_as_float((uint)Bt[(size_t)s2 * 64 + lane] << 16);
        const float f3 = __uint_as_float((uint)Bt[(size_t)s3 * 64 + lane] << 16);
        a += (f0 + f1) + (f2 + f3);
    }
    for (; e < e1; ++e)
        a += __uint_as_float((uint)Bt[(size_t)esrc[e] * 64 + lane] << 16);
    const float invd = (e1 > e0) ? 1.0f / (float)(e1 - e0) : 0.0f;
    out[(size_t)node * 64 + lane] += a * invd;
}

// ---------------- fp32 fallback path (small workspace) ----------------
__device__ inline float4 relu4f(float4 v) {
    v.x = fmaxf(v.x, 0.f); v.y = fmaxf(v.y, 0.f);
    v.z = fmaxf(v.z, 0.f); v.w = fmaxf(v.w, 0.f);
    return v;
}
template<int NCOL, bool RELU_IN, bool BIAS>
__global__ __launch_bounds__(256) void gemm_k(
    const float* in, const float* __restrict__ W,
    const float* __restrict__ bias, float* out)
{
    constexpr int K = 128;
    constexpr int QUADS = NCOL / 4;
    constexpr int G = 256 / QUADS;
    constexpr int RPT = 32 / G;
    __shared__ float Wlds[K * NCOL];
    {
        const float4* Wg = reinterpret_cast<const float4*>(W);
        float4* Wl = reinterpret_cast<float4*>(Wlds);
        #pragma unroll
        for (int i = 0; i < K * NCOL / 4 / 256; ++i)
            Wl[threadIdx.x + i * 256] = Wg[threadIdx.x + i * 256];
    }
    __syncthreads();
    const int tx = threadIdx.x % QUADS;
    const int ty = threadIdx.x / QUADS;
    const int row0 = blockIdx.x * 32;
    const float* rp[RPT];
    #pragma unroll
    for (int i = 0; i < RPT; ++i) rp[i] = in + (size_t)(row0 + ty + i * G) * K;
    float acc[RPT][4];
    #pragma unroll
    for (int i = 0; i < RPT; ++i) acc[i][0] = acc[i][1] = acc[i][2] = acc[i][3] = 0.f;
    #pragma unroll 2
    for (int kc = 0; kc < K; kc += 4) {
        float4 h4[RPT];
        #pragma unroll
        for (int i = 0; i < RPT; ++i) {
            h4[i] = *reinterpret_cast<const float4*>(rp[i] + kc);
            if (RELU_IN) h4[i] = relu4f(h4[i]);
        }
        #pragma unroll
        for (int kk = 0; kk < 4; ++kk) {
            const float4 w4 = *reinterpret_cast<const float4*>(&Wlds[(kc + kk) * NCOL + tx * 4]);
            #pragma unroll
            for (int i = 0; i < RPT; ++i) {
                const float hv = (&h4[i].x)[kk];
                acc[i][0] = fmaf(hv, w4.x, acc[i][0]);
                acc[i][1] = fmaf(hv, w4.y, acc[i][1]);
                acc[i][2] = fmaf(hv, w4.z, acc[i][2]);
                acc[i][3] = fmaf(hv, w4.w, acc[i][3]);
            }
        }
    }
    float4 b4 = make_float4(0.f, 0.f, 0.f, 0.f);
    if (BIAS) b4 = *reinterpret_cast<const float4*>(&bias[tx * 4]);
    #pragma unroll
    for (int i = 0; i < RPT; ++i) {
        const int r = row0 + ty + i * G;
        float4 o;
        o.x = acc[i][0] + b4.x; o.y = acc[i][1] + b4.y;
        o.z = acc[i][2] + b4.z; o.w = acc[i][3] + b4.w;
        *reinterpret_cast<float4*>(&out[(size_t)r * NCOL + tx * 4]) = o;
    }
}
__global__ void deg_k(const int* __restrict__ dst, float* __restrict__ deg, int E) {
    const int i = blockIdx.x * blockDim.x + threadIdx.x;
    if (i < E) atomicAdd(&deg[dst[i]], 1.0f);
}
__global__ void inv_k(float* deg, int n) {
    const int i = blockIdx.x * blockDim.x + threadIdx.x;
    if (i < n) deg[i] = 1.0f / fmaxf(deg[i], 1.0f);
}
__global__ __launch_bounds__(256) void scatter128_k(
    const int* __restrict__ src, const int* __restrict__ dst,
    const float* __restrict__ inv, const float* __restrict__ B, float* A, int E) {
    const int lane = threadIdx.x & 63;
    int w = (blockIdx.x * 256 + threadIdx.x) >> 6;
    const int nw = (gridDim.x * 256) >> 6;
    for (int e = w; e < E; e += nw) {
        const int s = src[e], d = dst[e];
        const float sc = inv[d];
        const float2 v = *reinterpret_cast<const float2*>(&B[(size_t)s * 128 + lane * 2]);
        atomicAdd(&A[(size_t)d * 128 + lane * 2    ], v.x * sc);
        atomicAdd(&A[(size_t)d * 128 + lane * 2 + 1], v.y * sc);
    }
}
__global__ __launch_bounds__(256) void scatter64_k(
    const int* __restrict__ src, const int* __restrict__ dst,
    const float* __restrict__ inv, const float* __restrict__ B, float* A, int E) {
    const int lane = threadIdx.x & 63;
    int w = (blockIdx.x * 256 + threadIdx.x) >> 6;
    const int nw = (gridDim.x * 256) >> 6;
    for (int e = w; e < E; e += nw) {
        const int s = src[e], d = dst[e];
        atomicAdd(&A[(size_t)d * 64 + lane], B[(size_t)s * 64 + lane] * inv[d]);
    }
}

extern "C" void kernel_launch(void* const* d_in, const int* in_sizes, int n_in,
                              void* d_out, int out_size, void* d_ws, size_t ws_size,
                              hipStream_t stream) {
    const float* x   = (const float*)d_in[0];
    const int*   src = (const int*)  d_in[1];
    const int*   dst = (const int*)  d_in[2];
    const float* ws0 = (const float*)d_in[3];
    const float* wn0 = (const float*)d_in[4];
    const float* b0  = (const float*)d_in[5];
    const float* ws1 = (const float*)d_in[6];
    const float* wn1 = (const float*)d_in[7];
    const float* b1  = (const float*)d_in[8];
    const float* ws2 = (const float*)d_in[9];
    const float* wn2 = (const float*)d_in[10];
    const float* b2  = (const float*)d_in[11];
    float* out = (float*)d_out;

    // workspace layout (byte offsets)
    const size_t O_BOFF = 0;          // (NB+1)*4 = 3132
    const size_t O_BWP  = 4096;       // NB*4
    const size_t O_BCNT = 8192;       // NB*4
    const size_t O_ROW  = 16384;      // (NN+1)*4 = 400004
    const size_t O_WF0  = 417792;     // 65536
    const size_t O_WF1  = 483328;     // 65536
    const size_t O_WF2  = 548864;     // 32768
    const size_t O_ESRC = 581632;     // 6400000
    const size_t O_A    = 7364864;    // 51200000 (pair buffer aliases front of A)
    const size_t O_BT   = 58564864;   // 25600000
    const size_t O_HB   = 84164864;   // 25600000
    const size_t NEED   = 109764864;

    if (ws_size >= NEED) {
        int*    boff = (int*)   ((char*)d_ws + O_BOFF);
        int*    bwp  = (int*)   ((char*)d_ws + O_BWP);
        int*    bcnt = (int*)   ((char*)d_ws + O_BCNT);
        int*    row  = (int*)   ((char*)d_ws + O_ROW);
        ushort* wf0  = (ushort*)((char*)d_ws + O_WF0);
        ushort* wf1  = (ushort*)((char*)d_ws + O_WF1);
        ushort* wf2  = (ushort*)((char*)d_ws + O_WF2);
        int*    esrc = (int*)   ((char*)d_ws + O_ESRC);
        float*  A    = (float*) ((char*)d_ws + O_A);
        int*    pb   = (int*)   ((char*)d_ws + O_A);   // dead before gemms run
        ushort* Bt   = (ushort*)((char*)d_ws + O_BT);
        ushort* Hb   = (ushort*)((char*)d_ws + O_HB);

        // bucketed CSR build
        hipMemsetAsync(bcnt, 0, NB * sizeof(int), stream);
        bucket_hist_k<<<256, 256, 0, stream>>>(dst, bcnt);
        bscan_k<<<1, 1024, 0, stream>>>(bcnt, boff, bwp);
        pair_scatter_k<<<(NE + 255) / 256, 256, 0, stream>>>(src, dst, bwp, pb);
        bucket_place_k<<<NB, 256, 0, stream>>>(boff, pb, row, esrc);

        // weight packs + x cast
        pack_w_k<128, 128><<<16, 256, 0, stream>>>(ws0, wn0, wf0);
        pack_w_k<128, 128><<<16, 256, 0, stream>>>(ws1, wn1, wf1);
        pack_w_k< 64,  64><<< 8, 256, 0, stream>>>(ws2, wn2, wf2);
        cvt_x_k<<<(NN * 16 + 255) / 256, 256, 0, stream>>>(x, Hb);

        const int GEMM_BLOCKS = (NN / 16 + 3) / 4;   // 1563
        const int AGG_BLOCKS  = (NN + 3) / 4;        // 25000

        // layer 0
        gemm_mfma_k<128, 128><<<GEMM_BLOCKS, 256, 0, stream>>>(Hb, wf0, b0, A, Bt);
        agg128_k<true><<<AGG_BLOCKS, 256, 0, stream>>>(row, esrc, Bt, A, Hb);
        // layer 1
        gemm_mfma_k<128, 128><<<GEMM_BLOCKS, 256, 0, stream>>>(Hb, wf1, b1, A, Bt);
        agg128_k<true><<<AGG_BLOCKS, 256, 0, stream>>>(row, esrc, Bt, A, Hb);
        // layer 2
        gemm_mfma_k<64, 64><<<GEMM_BLOCKS, 256, 0, stream>>>(Hb, wf2, b2, out, Bt);
        agg64_k<<<AGG_BLOCKS, 256, 0, stream>>>(row, esrc, Bt, out);
    } else {
        // fp32 atomic fallback
        float* inv = (float*)d_ws;
        float* H0  = (float*)((char*)d_ws + (1u << 20));
        float* Bf  = H0 + (size_t)NN * 128;
        const int GEMM_BLOCKS = NN / 32;
        const int SC_BLOCKS = 4096;
        hipMemsetAsync(inv, 0, NN * sizeof(float), stream);
        deg_k<<<(NE + 255) / 256, 256, 0, stream>>>(dst, inv, NE);
        inv_k<<<(NN + 255) / 256, 256, 0, stream>>>(inv, NN);
        gemm_k<128, false, false><<<GEMM_BLOCKS, 256, 0, stream>>>(x, wn0, nullptr, Bf);
        gemm_k<128, false, true ><<<GEMM_BLOCKS, 256, 0, stream>>>(x, ws0, b0, H0);
        scatter128_k<<<SC_BLOCKS, 256, 0, stream>>>(src, dst, inv, Bf, H0, NE);
        gemm_k<128, true, false><<<GEMM_BLOCKS, 256, 0, stream>>>(H0, wn1, nullptr, Bf);
        gemm_k<128, true, true ><<<GEMM_BLOCKS, 256, 0, stream>>>(H0, ws1, b1, H0);
        scatter128_k<<<SC_BLOCKS, 256, 0, stream>>>(src, dst, inv, Bf, H0, NE);
        gemm_k<64, true, false><<<GEMM_BLOCKS, 256, 0, stream>>>(H0, wn2, nullptr, Bf);
        gemm_k<64, true, true ><<<GEMM_BLOCKS, 256, 0, stream>>>(H0, ws2, b2, out);
        scatter64_k<<<SC_BLOCKS, 256, 0, stream>>>(src, dst, inv, Bf, out, NE);
    }
}

// Round 5
// 528.927 us; speedup vs baseline: 1.5994x; 1.5994x over previous
//
#include <hip/hip_runtime.h>

// GraphSAGE 3-layer forward. R5: deterministic two-level bucketed CSR build
// (no returning global atomics — R4's pair_scatter hit 782-counter atomic
// serialization, 376us) + bf16 MFMA fused GEMMs + bf16 gather aggregation.
// Per layer: [A | Bt] = H @ [Ws|Wn] (one fused MFMA GEMM, A fp32+bias, Bt bf16)
//            Hnext = relu(A + mean_{e:dst=d} Bt[src[e]]) stored bf16
//            (layer2: no relu, fp32 straight to d_out)

#define NN 100000
#define NE 1600000
#define BSH 7               // 128 dst-nodes per bucket
#define BND 128
#define NB  782             // ceil(100000/128)
#define NBLKS 128           // partition blocks for hist/scatter
#define EPB ((NE + NBLKS - 1) / NBLKS)   // 12500 edges per partition block
#define STOT (NB * NBLKS)   // 100096 scan entries
#define NSB ((STOT + 1023) / 1024)       // 98 scan blocks

typedef __attribute__((ext_vector_type(8))) short short8;
typedef __attribute__((ext_vector_type(4))) float f32x4;
typedef unsigned int uint;
typedef unsigned short ushort;

__device__ inline ushort f2bf(float f) {
    uint u = __float_as_uint(f);
    u += 0x7FFFu + ((u >> 16) & 1u);
    return (ushort)(u >> 16);
}
__device__ inline float bf_lo(uint w) { return __uint_as_float(w << 16); }
__device__ inline float bf_hi(uint w) { return __uint_as_float(w & 0xFFFF0000u); }

// ---------------- deterministic bucketed CSR build ----------------
// Phase 1: private per-block bucket histograms (LDS), plain stores to histG
__global__ __launch_bounds__(256) void phist_k(const int* __restrict__ dst,
                                               int* __restrict__ histG) {
    __shared__ int h[NB];
    const int t = threadIdx.x;
    for (int i = t; i < NB; i += 256) h[i] = 0;
    __syncthreads();
    const int blk = blockIdx.x;
    const int e0 = blk * EPB;
    const int e1 = min(e0 + EPB, NE);
    for (int e = e0 + t; e < e1; e += 256)
        atomicAdd(&h[dst[e] >> BSH], 1);
    __syncthreads();
    for (int i = t; i < NB; i += 256)
        histG[i * NBLKS + blk] = h[i];
}

// Phase 2: exclusive scan of histG[STOT] in place (3-stage)
__global__ __launch_bounds__(256) void scan1_k(int* __restrict__ data, int* __restrict__ blksum) {
    __shared__ int lds[256];
    const int t = threadIdx.x;
    const int base = blockIdx.x * 1024 + t * 4;
    int v[4];
    #pragma unroll
    for (int i = 0; i < 4; ++i) {
        const int idx = base + i;
        v[i] = (idx < STOT) ? data[idx] : 0;
    }
    const int s = v[0] + v[1] + v[2] + v[3];
    lds[t] = s;
    __syncthreads();
    #pragma unroll
    for (int off = 1; off < 256; off <<= 1) {
        const int cur = lds[t];
        const int y = (t >= off) ? lds[t - off] : 0;
        __syncthreads();
        lds[t] = cur + y;
        __syncthreads();
    }
    const int incl = lds[t];
    if (t == 255) blksum[blockIdx.x] = incl;
    int run = incl - s;
    #pragma unroll
    for (int i = 0; i < 4; ++i) {
        const int idx = base + i;
        if (idx < STOT) data[idx] = run;
        run += v[i];
    }
}

__global__ __launch_bounds__(128) void scan2_k(int* blksum, int nb) {
    __shared__ int lds[128];
    const int t = threadIdx.x;
    const int s = (t < nb) ? blksum[t] : 0;
    lds[t] = s;
    __syncthreads();
    #pragma unroll
    for (int off = 1; off < 128; off <<= 1) {
        const int cur = lds[t];
        const int y = (t >= off) ? lds[t - off] : 0;
        __syncthreads();
        lds[t] = cur + y;
        __syncthreads();
    }
    if (t < nb) blksum[t] = lds[t] - s;
}

__global__ __launch_bounds__(256) void scan3_k(int* __restrict__ data, const int* __restrict__ blksum) {
    const int t = threadIdx.x;
    const int add = blksum[blockIdx.x];
    const int base = blockIdx.x * 1024 + t * 4;
    #pragma unroll
    for (int i = 0; i < 4; ++i) {
        const int idx = base + i;
        if (idx < STOT) data[idx] += add;
    }
}

// Phase 3: scatter packed (src<<7 | dst&127) using scanned private bases.
// Only LDS atomics; each (block,bucket) writes a contiguous run in pb.
__global__ __launch_bounds__(256) void pscatter_k(const int* __restrict__ src,
                                                  const int* __restrict__ dst,
                                                  const int* __restrict__ histG,
                                                  int* __restrict__ pb) {
    __shared__ int wc[NB];
    const int t = threadIdx.x;
    const int blk = blockIdx.x;
    for (int i = t; i < NB; i += 256) wc[i] = histG[i * NBLKS + blk];
    __syncthreads();
    const int e0 = blk * EPB;
    const int e1 = min(e0 + EPB, NE);
    for (int e = e0 + t; e < e1; e += 256) {
        const int d = dst[e];
        const int pos = atomicAdd(&wc[d >> BSH], 1);
        pb[pos] = (src[e] << BSH) | (d & (BND - 1));
    }
}

// Phase 4: one block per bucket — local count, scan, place esrc into the
// bucket's contiguous window (L2-resident), emit row[]
__global__ __launch_bounds__(256) void bucket_place_k(const int* __restrict__ histG,
                                                      const int* __restrict__ pb,
                                                      int* __restrict__ row,
                                                      int* __restrict__ esrc) {
    __shared__ int cnt[BND], wc[BND], excl[BND], scan[BND];
    const int b = blockIdx.x;
    const int t = threadIdx.x;
    if (t < BND) { cnt[t] = 0; wc[t] = 0; }
    __syncthreads();
    const int s0 = histG[b * NBLKS];
    const int s1 = (b + 1 < NB) ? histG[(b + 1) * NBLKS] : NE;
    for (int e = s0 + t; e < s1; e += 256)
        atomicAdd(&cnt[pb[e] & (BND - 1)], 1);
    __syncthreads();
    if (t < BND) scan[t] = cnt[t];
    __syncthreads();
    for (int off = 1; off < BND; off <<= 1) {
        int nv = 0;
        if (t < BND) {
            nv = scan[t];
            if (t >= off) nv += scan[t - off];
        }
        __syncthreads();
        if (t < BND) scan[t] = nv;
        __syncthreads();
    }
    if (t < BND) {
        const int ex = scan[t] - cnt[t];
        excl[t] = ex;
        const int node = b * BND + t;
        if (node <= NN) row[node] = s0 + ex;   // node==NN lands on row[NN]=NE
    }
    __syncthreads();
    for (int e = s0 + t; e < s1; e += 256) {
        const int p = pb[e];
        const int dl = p & (BND - 1);
        const int pos = s0 + excl[dl] + atomicAdd(&wc[dl], 1);
        esrc[pos] = p >> BSH;
    }
}

// ---------------- fp32 -> bf16 feature convert (x -> Hb) ----------------
__global__ __launch_bounds__(256) void cvt_x_k(const float* __restrict__ x, ushort* __restrict__ hb) {
    const int idx = blockIdx.x * 256 + threadIdx.x;
    if (idx >= NN * 16) return;
    const float4* xp = (const float4*)x;
    const float4 a = xp[idx * 2];
    const float4 b = xp[idx * 2 + 1];
    uint4 o;
    o.x = (uint)f2bf(a.x) | ((uint)f2bf(a.y) << 16);
    o.y = (uint)f2bf(a.z) | ((uint)f2bf(a.w) << 16);
    o.z = (uint)f2bf(b.x) | ((uint)f2bf(b.y) << 16);
    o.w = (uint)f2bf(b.z) | ((uint)f2bf(b.w) << 16);
    ((uint4*)hb)[idx] = o;
}

// ---------------- weight pack: [Ws|Wn] fp32 -> bf16 B-fragment-major ----------------
template<int NCS, int NCN>
__global__ __launch_bounds__(256) void pack_w_k(const float* __restrict__ ws, const float* __restrict__ wn,
                                                ushort* __restrict__ wf) {
    constexpr int TOTAL = ((NCS + NCN) / 16) * 4 * 64;
    const int idx = blockIdx.x * 256 + threadIdx.x;
    if (idx >= TOTAL) return;
    const int l = idx & 63;
    const int f = idx >> 6;
    const int kt = f & 3;
    const int ct = f >> 2;
    const int n = ct * 16 + (l & 15);
    const int k0 = kt * 32 + (l >> 4) * 8;
    uint w[4];
    #pragma unroll
    for (int p = 0; p < 4; ++p) {
        const int k = k0 + p * 2;
        float v0, v1;
        if (n < NCS) { v0 = ws[k * NCS + n];        v1 = ws[(k + 1) * NCS + n]; }
        else         { v0 = wn[k * NCN + (n - NCS)]; v1 = wn[(k + 1) * NCN + (n - NCS)]; }
        w[p] = (uint)f2bf(v0) | ((uint)f2bf(v1) << 16);
    }
    uint4 o; o.x = w[0]; o.y = w[1]; o.z = w[2]; o.w = w[3];
    ((uint4*)wf)[idx] = o;
}

// ---------------- fused MFMA GEMM: [A | Bt] = H @ Wcat ----------------
template<int NCS, int NCN>
__global__ __launch_bounds__(256) void gemm_mfma_k(
    const ushort* __restrict__ H, const ushort* __restrict__ Wf,
    const float* __restrict__ bias, float* __restrict__ A, ushort* __restrict__ Bt)
{
    constexpr int NCT = (NCS + NCN) / 16;
    const int g = (blockIdx.x * 256 + threadIdx.x) >> 6;
    if (g >= NN / 16) return;
    const int lane = threadIdx.x & 63;
    const int m = lane & 15;
    const int q = lane >> 4;

    const short8* hp = (const short8*)(H + (size_t)(g * 16 + m) * 128);
    short8 af[4];
    #pragma unroll
    for (int kt = 0; kt < 4; ++kt) af[kt] = hp[kt * 4 + q];

    f32x4 acc[NCT];
    #pragma unroll
    for (int i = 0; i < NCT; ++i) acc[i] = (f32x4){0.f, 0.f, 0.f, 0.f};

    const short8* wp = (const short8*)Wf;
    #pragma unroll
    for (int ct = 0; ct < NCT; ++ct) {
        #pragma unroll
        for (int kt = 0; kt < 4; ++kt) {
            const short8 bf = wp[(ct * 4 + kt) * 64 + lane];
            acc[ct] = __builtin_amdgcn_mfma_f32_16x16x32_bf16(af[kt], bf, acc[ct], 0, 0, 0);
        }
    }

    const int r0 = g * 16 + q * 4;
    #pragma unroll
    for (int ct = 0; ct < NCS / 16; ++ct) {
        const int c = ct * 16 + m;
        const float bv = bias[c];
        #pragma unroll
        for (int r = 0; r < 4; ++r)
            A[(size_t)(r0 + r) * NCS + c] = acc[ct][r] + bv;
    }
    #pragma unroll
    for (int ct = NCS / 16; ct < NCT; ++ct) {
        const int c = ct * 16 + m - NCS;
        #pragma unroll
        for (int r = 0; r < 4; ++r)
            Bt[(size_t)(r0 + r) * NCN + c] = f2bf(acc[ct][r]);
    }
}

// ---------------- aggregation ----------------
template<bool RELU>
__global__ __launch_bounds__(256) void agg128_k(
    const int* __restrict__ row, const int* __restrict__ esrc,
    const ushort* __restrict__ Bt, const float* __restrict__ A, ushort* __restrict__ Hb)
{
    const int node = (blockIdx.x * 256 + threadIdx.x) >> 6;
    if (node >= NN) return;
    const int lane = threadIdx.x & 63;
    const int e0 = row[node];
    const int e1 = row[node + 1];
    const uint* B32 = (const uint*)Bt;
    float a0 = 0.f, a1 = 0.f;
    int e = e0;
    for (; e + 4 <= e1; e += 4) {
        const int s0 = esrc[e], s1 = esrc[e + 1], s2 = esrc[e + 2], s3 = esrc[e + 3];
        const uint w0 = B32[(size_t)s0 * 64 + lane];
        const uint w1 = B32[(size_t)s1 * 64 + lane];
        const uint w2 = B32[(size_t)s2 * 64 + lane];
        const uint w3 = B32[(size_t)s3 * 64 + lane];
        a0 += (bf_lo(w0) + bf_lo(w1)) + (bf_lo(w2) + bf_lo(w3));
        a1 += (bf_hi(w0) + bf_hi(w1)) + (bf_hi(w2) + bf_hi(w3));
    }
    for (; e < e1; ++e) {
        const uint w = B32[(size_t)esrc[e] * 64 + lane];
        a0 += bf_lo(w);
        a1 += bf_hi(w);
    }
    const float invd = (e1 > e0) ? 1.0f / (float)(e1 - e0) : 0.0f;
    const float2 av = *(const float2*)(A + (size_t)node * 128 + lane * 2);
    float v0 = av.x + a0 * invd;
    float v1 = av.y + a1 * invd;
    if (RELU) { v0 = fmaxf(v0, 0.f); v1 = fmaxf(v1, 0.f); }
    ((uint*)Hb)[(size_t)node * 64 + lane] = (uint)f2bf(v0) | ((uint)f2bf(v1) << 16);
}

__global__ __launch_bounds__(256) void agg64_k(
    const int* __restrict__ row, const int* __restrict__ esrc,
    const ushort* __restrict__ Bt, float* __restrict__ out)
{
    const int node = (blockIdx.x * 256 + threadIdx.x) >> 6;
    if (node >= NN) return;
    const int lane = threadIdx.x & 63;
    const int e0 = row[node];
    const int e1 = row[node + 1];
    float a = 0.f;
    int e = e0;
    for (; e + 4 <= e1; e += 4) {
        const int s0 = esrc[e], s1 = esrc[e + 1], s2 = esrc[e + 2], s3 = esrc[e + 3];
        const float f0 = __uint_as_float((uint)Bt[(size_t)s0 * 64 + lane] << 16);
        const float f1 = __uint_as_float((uint)Bt[(size_t)s1 * 64 + lane] << 16);
        const float f2 = __uint_as_float((uint)Bt[(size_t)s2 * 64 + lane] << 16);
        const float f3 = __uint_as_float((uint)Bt[(size_t)s3 * 64 + lane] << 16);
        a += (f0 + f1) + (f2 + f3);
    }
    for (; e < e1; ++e)
        a += __uint_as_float((uint)Bt[(size_t)esrc[e] * 64 + lane] << 16);
    const float invd = (e1 > e0) ? 1.0f / (float)(e1 - e0) : 0.0f;
    out[(size_t)node * 64 + lane] += a * invd;
}

// ---------------- fp32 fallback path (small workspace) ----------------
__device__ inline float4 relu4f(float4 v) {
    v.x = fmaxf(v.x, 0.f); v.y = fmaxf(v.y, 0.f);
    v.z = fmaxf(v.z, 0.f); v.w = fmaxf(v.w, 0.f);
    return v;
}
template<int NCOL, bool RELU_IN, bool BIAS>
__global__ __launch_bounds__(256) void gemm_k(
    const float* in, const float* __restrict__ W,
    const float* __restrict__ bias, float* out)
{
    constexpr int K = 128;
    constexpr int QUADS = NCOL / 4;
    constexpr int G = 256 / QUADS;
    constexpr int RPT = 32 / G;
    __shared__ float Wlds[K * NCOL];
    {
        const float4* Wg = reinterpret_cast<const float4*>(W);
        float4* Wl = reinterpret_cast<float4*>(Wlds);
        #pragma unroll
        for (int i = 0; i < K * NCOL / 4 / 256; ++i)
            Wl[threadIdx.x + i * 256] = Wg[threadIdx.x + i * 256];
    }
    __syncthreads();
    const int tx = threadIdx.x % QUADS;
    const int ty = threadIdx.x / QUADS;
    const int row0 = blockIdx.x * 32;
    const float* rp[RPT];
    #pragma unroll
    for (int i = 0; i < RPT; ++i) rp[i] = in + (size_t)(row0 + ty + i * G) * K;
    float acc[RPT][4];
    #pragma unroll
    for (int i = 0; i < RPT; ++i) acc[i][0] = acc[i][1] = acc[i][2] = acc[i][3] = 0.f;
    #pragma unroll 2
    for (int kc = 0; kc < K; kc += 4) {
        float4 h4[RPT];
        #pragma unroll
        for (int i = 0; i < RPT; ++i) {
            h4[i] = *reinterpret_cast<const float4*>(rp[i] + kc);
            if (RELU_IN) h4[i] = relu4f(h4[i]);
        }
        #pragma unroll
        for (int kk = 0; kk < 4; ++kk) {
            const float4 w4 = *reinterpret_cast<const float4*>(&Wlds[(kc + kk) * NCOL + tx * 4]);
            #pragma unroll
            for (int i = 0; i < RPT; ++i) {
                const float hv = (&h4[i].x)[kk];
                acc[i][0] = fmaf(hv, w4.x, acc[i][0]);
                acc[i][1] = fmaf(hv, w4.y, acc[i][1]);
                acc[i][2] = fmaf(hv, w4.z, acc[i][2]);
                acc[i][3] = fmaf(hv, w4.w, acc[i][3]);
            }
        }
    }
    float4 b4 = make_float4(0.f, 0.f, 0.f, 0.f);
    if (BIAS) b4 = *reinterpret_cast<const float4*>(&bias[tx * 4]);
    #pragma unroll
    for (int i = 0; i < RPT; ++i) {
        const int r = row0 + ty + i * G;
        float4 o;
        o.x = acc[i][0] + b4.x; o.y = acc[i][1] + b4.y;
        o.z = acc[i][2] + b4.z; o.w = acc[i][3] + b4.w;
        *reinterpret_cast<float4*>(&out[(size_t)r * NCOL + tx * 4]) = o;
    }
}
__global__ void deg_k(const int* __restrict__ dst, float* __restrict__ deg, int E) {
    const int i = blockIdx.x * blockDim.x + threadIdx.x;
    if (i < E) atomicAdd(&deg[dst[i]], 1.0f);
}
__global__ void inv_k(float* deg, int n) {
    const int i = blockIdx.x * blockDim.x + threadIdx.x;
    if (i < n) deg[i] = 1.0f / fmaxf(deg[i], 1.0f);
}
__global__ __launch_bounds__(256) void scatter128_k(
    const int* __restrict__ src, const int* __restrict__ dst,
    const float* __restrict__ inv, const float* __restrict__ B, float* A, int E) {
    const int lane = threadIdx.x & 63;
    int w = (blockIdx.x * 256 + threadIdx.x) >> 6;
    const int nw = (gridDim.x * 256) >> 6;
    for (int e = w; e < E; e += nw) {
        const int s = src[e], d = dst[e];
        const float sc = inv[d];
        const float2 v = *reinterpret_cast<const float2*>(&B[(size_t)s * 128 + lane * 2]);
        atomicAdd(&A[(size_t)d * 128 + lane * 2    ], v.x * sc);
        atomicAdd(&A[(size_t)d * 128 + lane * 2 + 1], v.y * sc);
    }
}
__global__ __launch_bounds__(256) void scatter64_k(
    const int* __restrict__ src, const int* __restrict__ dst,
    const float* __restrict__ inv, const float* __restrict__ B, float* A, int E) {
    const int lane = threadIdx.x & 63;
    int w = (blockIdx.x * 256 + threadIdx.x) >> 6;
    const int nw = (gridDim.x * 256) >> 6;
    for (int e = w; e < E; e += nw) {
        const int s = src[e], d = dst[e];
        atomicAdd(&A[(size_t)d * 64 + lane], B[(size_t)s * 64 + lane] * inv[d]);
    }
}

extern "C" void kernel_launch(void* const* d_in, const int* in_sizes, int n_in,
                              void* d_out, int out_size, void* d_ws, size_t ws_size,
                              hipStream_t stream) {
    const float* x   = (const float*)d_in[0];
    const int*   src = (const int*)  d_in[1];
    const int*   dst = (const int*)  d_in[2];
    const float* ws0 = (const float*)d_in[3];
    const float* wn0 = (const float*)d_in[4];
    const float* b0  = (const float*)d_in[5];
    const float* ws1 = (const float*)d_in[6];
    const float* wn1 = (const float*)d_in[7];
    const float* b1  = (const float*)d_in[8];
    const float* ws2 = (const float*)d_in[9];
    const float* wn2 = (const float*)d_in[10];
    const float* b2  = (const float*)d_in[11];
    float* out = (float*)d_out;

    // workspace layout (byte offsets)
    const size_t O_BLK  = 4096;       // scan blocksums (392B)
    const size_t O_ROW  = 16384;      // (NN+1)*4 = 400004
    const size_t O_WF0  = 417792;     // 65536
    const size_t O_WF1  = 483328;     // 65536
    const size_t O_WF2  = 548864;     // 32768
    const size_t O_ESRC = 581632;     // 6400000
    const size_t O_A    = 7364864;    // 51200000  (pb + histG alias its front)
    const size_t O_PB   = O_A;                       // 6400000
    const size_t O_HIST = O_A + (8u << 20);          // 400384 (dead before gemms)
    const size_t O_BT   = 58564864;   // 25600000
    const size_t O_HB   = 84164864;   // 25600000
    const size_t NEED   = 109764864;

    if (ws_size >= NEED) {
        int*    blks  = (int*)   ((char*)d_ws + O_BLK);
        int*    row   = (int*)   ((char*)d_ws + O_ROW);
        ushort* wf0   = (ushort*)((char*)d_ws + O_WF0);
        ushort* wf1   = (ushort*)((char*)d_ws + O_WF1);
        ushort* wf2   = (ushort*)((char*)d_ws + O_WF2);
        int*    esrc  = (int*)   ((char*)d_ws + O_ESRC);
        float*  A     = (float*) ((char*)d_ws + O_A);
        int*    pb    = (int*)   ((char*)d_ws + O_PB);
        int*    histG = (int*)   ((char*)d_ws + O_HIST);
        ushort* Bt    = (ushort*)((char*)d_ws + O_BT);
        ushort* Hb    = (ushort*)((char*)d_ws + O_HB);

        // deterministic bucketed CSR build
        phist_k<<<NBLKS, 256, 0, stream>>>(dst, histG);
        scan1_k<<<NSB, 256, 0, stream>>>(histG, blks);
        scan2_k<<<1, 128, 0, stream>>>(blks, NSB);
        scan3_k<<<NSB, 256, 0, stream>>>(histG, blks);
        pscatter_k<<<NBLKS, 256, 0, stream>>>(src, dst, histG, pb);
        bucket_place_k<<<NB, 256, 0, stream>>>(histG, pb, row, esrc);

        // weight packs + x cast
        pack_w_k<128, 128><<<16, 256, 0, stream>>>(ws0, wn0, wf0);
        pack_w_k<128, 128><<<16, 256, 0, stream>>>(ws1, wn1, wf1);
        pack_w_k< 64,  64><<< 8, 256, 0, stream>>>(ws2, wn2, wf2);
        cvt_x_k<<<(NN * 16 + 255) / 256, 256, 0, stream>>>(x, Hb);

        const int GEMM_BLOCKS = (NN / 16 + 3) / 4;   // 1563
        const int AGG_BLOCKS  = (NN + 3) / 4;        // 25000

        // layer 0
        gemm_mfma_k<128, 128><<<GEMM_BLOCKS, 256, 0, stream>>>(Hb, wf0, b0, A, Bt);
        agg128_k<true><<<AGG_BLOCKS, 256, 0, stream>>>(row, esrc, Bt, A, Hb);
        // layer 1
        gemm_mfma_k<128, 128><<<GEMM_BLOCKS, 256, 0, stream>>>(Hb, wf1, b1, A, Bt);
        agg128_k<true><<<AGG_BLOCKS, 256, 0, stream>>>(row, esrc, Bt, A, Hb);
        // layer 2
        gemm_mfma_k<64, 64><<<GEMM_BLOCKS, 256, 0, stream>>>(Hb, wf2, b2, out, Bt);
        agg64_k<<<AGG_BLOCKS, 256, 0, stream>>>(row, esrc, Bt, out);
    } else {
        // fp32 atomic fallback
        float* inv = (float*)d_ws;
        float* H0  = (float*)((char*)d_ws + (1u << 20));
        float* Bf  = H0 + (size_t)NN * 128;
        const int GEMM_BLOCKS = NN / 32;
        const int SC_BLOCKS = 4096;
        hipMemsetAsync(inv, 0, NN * sizeof(float), stream);
        deg_k<<<(NE + 255) / 256, 256, 0, stream>>>(dst, inv, NE);
        inv_k<<<(NN + 255) / 256, 256, 0, stream>>>(inv, NN);
        gemm_k<128, false, false><<<GEMM_BLOCKS, 256, 0, stream>>>(x, wn0, nullptr, Bf);
        gemm_k<128, false, true ><<<GEMM_BLOCKS, 256, 0, stream>>>(x, ws0, b0, H0);
        scatter128_k<<<SC_BLOCKS, 256, 0, stream>>>(src, dst, inv, Bf, H0, NE);
        gemm_k<128, true, false><<<GEMM_BLOCKS, 256, 0, stream>>>(H0, wn1, nullptr, Bf);
        gemm_k<128, true, true ><<<GEMM_BLOCKS, 256, 0, stream>>>(H0, ws1, b1, H0);
        scatter128_k<<<SC_BLOCKS, 256, 0, stream>>>(src, dst, inv, Bf, H0, NE);
        gemm_k<64, true, false><<<GEMM_BLOCKS, 256, 0, stream>>>(H0, wn2, nullptr, Bf);
        gemm_k<64, true, true ><<<GEMM_BLOCKS, 256, 0, stream>>>(H0, ws2, b2, out);
        scatter64_k<<<SC_BLOCKS, 256, 0, stream>>>(src, dst, inv, Bf, out, NE);
    }
}

// Round 6
// 485.014 us; speedup vs baseline: 1.7443x; 1.0905x over previous
//
#include <hip/hip_runtime.h>

// GraphSAGE 3-layer forward. R6: agg gather unroll x8 (MLP), layer-0 GEMM
// reads fp32 x directly (cvt_x pass removed), A stored bf16 for layers 0/1,
// single fused weight-pack kernel. Deterministic bucketed CSR build (R5).
// Per layer: [A | Bt] = H @ [Ws|Wn] (one fused MFMA GEMM)
//            Hnext = relu(A + mean_{e:dst=d} Bt[src[e]]) stored bf16
//            (layer2: A fp32 straight to d_out, no relu)

#define NN 100000
#define NE 1600000
#define BSH 7               // 128 dst-nodes per bucket
#define BND 128
#define NB  782             // ceil(100000/128)
#define NBLKS 128           // partition blocks for hist/scatter
#define EPB ((NE + NBLKS - 1) / NBLKS)   // 12500 edges per partition block
#define STOT (NB * NBLKS)   // 100096 scan entries
#define NSB ((STOT + 1023) / 1024)       // 98 scan blocks

typedef __attribute__((ext_vector_type(8))) short short8;
typedef __attribute__((ext_vector_type(4))) float f32x4;
typedef unsigned int uint;
typedef unsigned short ushort;

__device__ inline ushort f2bf(float f) {
    uint u = __float_as_uint(f);
    u += 0x7FFFu + ((u >> 16) & 1u);
    return (ushort)(u >> 16);
}
__device__ inline float bf_lo(uint w) { return __uint_as_float(w << 16); }
__device__ inline float bf_hi(uint w) { return __uint_as_float(w & 0xFFFF0000u); }

// ---------------- deterministic bucketed CSR build (R5, unchanged) ----------------
__global__ __launch_bounds__(256) void phist_k(const int* __restrict__ dst,
                                               int* __restrict__ histG) {
    __shared__ int h[NB];
    const int t = threadIdx.x;
    for (int i = t; i < NB; i += 256) h[i] = 0;
    __syncthreads();
    const int blk = blockIdx.x;
    const int e0 = blk * EPB;
    const int e1 = min(e0 + EPB, NE);
    for (int e = e0 + t; e < e1; e += 256)
        atomicAdd(&h[dst[e] >> BSH], 1);
    __syncthreads();
    for (int i = t; i < NB; i += 256)
        histG[i * NBLKS + blk] = h[i];
}

__global__ __launch_bounds__(256) void scan1_k(int* __restrict__ data, int* __restrict__ blksum) {
    __shared__ int lds[256];
    const int t = threadIdx.x;
    const int base = blockIdx.x * 1024 + t * 4;
    int v[4];
    #pragma unroll
    for (int i = 0; i < 4; ++i) {
        const int idx = base + i;
        v[i] = (idx < STOT) ? data[idx] : 0;
    }
    const int s = v[0] + v[1] + v[2] + v[3];
    lds[t] = s;
    __syncthreads();
    #pragma unroll
    for (int off = 1; off < 256; off <<= 1) {
        const int cur = lds[t];
        const int y = (t >= off) ? lds[t - off] : 0;
        __syncthreads();
        lds[t] = cur + y;
        __syncthreads();
    }
    const int incl = lds[t];
    if (t == 255) blksum[blockIdx.x] = incl;
    int run = incl - s;
    #pragma unroll
    for (int i = 0; i < 4; ++i) {
        const int idx = base + i;
        if (idx < STOT) data[idx] = run;
        run += v[i];
    }
}

__global__ __launch_bounds__(128) void scan2_k(int* blksum, int nb) {
    __shared__ int lds[128];
    const int t = threadIdx.x;
    const int s = (t < nb) ? blksum[t] : 0;
    lds[t] = s;
    __syncthreads();
    #pragma unroll
    for (int off = 1; off < 128; off <<= 1) {
        const int cur = lds[t];
        const int y = (t >= off) ? lds[t - off] : 0;
        __syncthreads();
        lds[t] = cur + y;
        __syncthreads();
    }
    if (t < nb) blksum[t] = lds[t] - s;
}

__global__ __launch_bounds__(256) void scan3_k(int* __restrict__ data, const int* __restrict__ blksum) {
    const int t = threadIdx.x;
    const int add = blksum[blockIdx.x];
    const int base = blockIdx.x * 1024 + t * 4;
    #pragma unroll
    for (int i = 0; i < 4; ++i) {
        const int idx = base + i;
        if (idx < STOT) data[idx] += add;
    }
}

__global__ __launch_bounds__(256) void pscatter_k(const int* __restrict__ src,
                                                  const int* __restrict__ dst,
                                                  const int* __restrict__ histG,
                                                  int* __restrict__ pb) {
    __shared__ int wc[NB];
    const int t = threadIdx.x;
    const int blk = blockIdx.x;
    for (int i = t; i < NB; i += 256) wc[i] = histG[i * NBLKS + blk];
    __syncthreads();
    const int e0 = blk * EPB;
    const int e1 = min(e0 + EPB, NE);
    for (int e = e0 + t; e < e1; e += 256) {
        const int d = dst[e];
        const int pos = atomicAdd(&wc[d >> BSH], 1);
        pb[pos] = (src[e] << BSH) | (d & (BND - 1));
    }
}

__global__ __launch_bounds__(256) void bucket_place_k(const int* __restrict__ histG,
                                                      const int* __restrict__ pb,
                                                      int* __restrict__ row,
                                                      int* __restrict__ esrc) {
    __shared__ int cnt[BND], wc[BND], excl[BND], scan[BND];
    const int b = blockIdx.x;
    const int t = threadIdx.x;
    if (t < BND) { cnt[t] = 0; wc[t] = 0; }
    __syncthreads();
    const int s0 = histG[b * NBLKS];
    const int s1 = (b + 1 < NB) ? histG[(b + 1) * NBLKS] : NE;
    for (int e = s0 + t; e < s1; e += 256)
        atomicAdd(&cnt[pb[e] & (BND - 1)], 1);
    __syncthreads();
    if (t < BND) scan[t] = cnt[t];
    __syncthreads();
    for (int off = 1; off < BND; off <<= 1) {
        int nv = 0;
        if (t < BND) {
            nv = scan[t];
            if (t >= off) nv += scan[t - off];
        }
        __syncthreads();
        if (t < BND) scan[t] = nv;
        __syncthreads();
    }
    if (t < BND) {
        const int ex = scan[t] - cnt[t];
        excl[t] = ex;
        const int node = b * BND + t;
        if (node <= NN) row[node] = s0 + ex;
    }
    __syncthreads();
    for (int e = s0 + t; e < s1; e += 256) {
        const int p = pb[e];
        const int dl = p & (BND - 1);
        const int pos = s0 + excl[dl] + atomicAdd(&wc[dl], 1);
        esrc[pos] = p >> BSH;
    }
}

// ---------------- fused weight pack: all three layers, one launch ----------------
// frag f = ct*4+kt ; within frag, lane l holds B[k=kt*32+(l>>4)*8+j][n=ct*16+(l&15)]
__global__ __launch_bounds__(256) void pack_all_k(
    const float* __restrict__ ws0, const float* __restrict__ wn0, ushort* __restrict__ wf0,
    const float* __restrict__ ws1, const float* __restrict__ wn1, ushort* __restrict__ wf1,
    const float* __restrict__ ws2, const float* __restrict__ wn2, ushort* __restrict__ wf2)
{
    const int b = blockIdx.x;
    const float *ws, *wn; ushort* wf; int ncs, idx;
    if (b < 16)      { ws = ws0; wn = wn0; wf = wf0; ncs = 128; idx = b * 256 + threadIdx.x; }
    else if (b < 32) { ws = ws1; wn = wn1; wf = wf1; ncs = 128; idx = (b - 16) * 256 + threadIdx.x; }
    else             { ws = ws2; wn = wn2; wf = wf2; ncs = 64;  idx = (b - 32) * 256 + threadIdx.x; }
    const int total = (2 * ncs / 16) * 4 * 64;
    if (idx >= total) return;
    const int l = idx & 63;
    const int f = idx >> 6;
    const int kt = f & 3;
    const int ct = f >> 2;
    const int n = ct * 16 + (l & 15);
    const int k0 = kt * 32 + (l >> 4) * 8;
    uint w[4];
    #pragma unroll
    for (int p = 0; p < 4; ++p) {
        const int k = k0 + p * 2;
        float v0, v1;
        if (n < ncs) { v0 = ws[k * ncs + n];         v1 = ws[(k + 1) * ncs + n]; }
        else         { v0 = wn[k * ncs + (n - ncs)]; v1 = wn[(k + 1) * ncs + (n - ncs)]; }
        w[p] = (uint)f2bf(v0) | ((uint)f2bf(v1) << 16);
    }
    uint4 o; o.x = w[0]; o.y = w[1]; o.z = w[2]; o.w = w[3];
    ((uint4*)wf)[idx] = o;
}

// ---------------- fused MFMA GEMM: [A | Bt] = H @ Wcat ----------------
// XF32: input is fp32 (layer 0, reads x directly). ABF: A stored bf16.
template<int NCS, int NCN, bool XF32, bool ABF>
__global__ __launch_bounds__(256) void gemm_mfma_k(
    const void* __restrict__ Hv, const ushort* __restrict__ Wf,
    const float* __restrict__ bias, void* __restrict__ Av, ushort* __restrict__ Bt)
{
    constexpr int NCT = (NCS + NCN) / 16;
    const int g = (blockIdx.x * 256 + threadIdx.x) >> 6;
    if (g >= NN / 16) return;
    const int lane = threadIdx.x & 63;
    const int m = lane & 15;
    const int q = lane >> 4;

    short8 af[4];
    if (XF32) {
        const float* hp = (const float*)Hv + (size_t)(g * 16 + m) * 128;
        #pragma unroll
        for (int kt = 0; kt < 4; ++kt) {
            const float4 f0 = *(const float4*)(hp + kt * 32 + q * 8);
            const float4 f1 = *(const float4*)(hp + kt * 32 + q * 8 + 4);
            short8 v;
            v[0] = (short)f2bf(f0.x); v[1] = (short)f2bf(f0.y);
            v[2] = (short)f2bf(f0.z); v[3] = (short)f2bf(f0.w);
            v[4] = (short)f2bf(f1.x); v[5] = (short)f2bf(f1.y);
            v[6] = (short)f2bf(f1.z); v[7] = (short)f2bf(f1.w);
            af[kt] = v;
        }
    } else {
        const short8* hp = (const short8*)((const ushort*)Hv + (size_t)(g * 16 + m) * 128);
        #pragma unroll
        for (int kt = 0; kt < 4; ++kt) af[kt] = hp[kt * 4 + q];
    }

    f32x4 acc[NCT];
    #pragma unroll
    for (int i = 0; i < NCT; ++i) acc[i] = (f32x4){0.f, 0.f, 0.f, 0.f};

    const short8* wp = (const short8*)Wf;
    #pragma unroll
    for (int ct = 0; ct < NCT; ++ct) {
        #pragma unroll
        for (int kt = 0; kt < 4; ++kt) {
            const short8 bf = wp[(ct * 4 + kt) * 64 + lane];
            acc[ct] = __builtin_amdgcn_mfma_f32_16x16x32_bf16(af[kt], bf, acc[ct], 0, 0, 0);
        }
    }

    const int r0 = g * 16 + q * 4;
    #pragma unroll
    for (int ct = 0; ct < NCS / 16; ++ct) {
        const int c = ct * 16 + m;
        const float bv = bias[c];
        #pragma unroll
        for (int r = 0; r < 4; ++r) {
            const float v = acc[ct][r] + bv;
            if (ABF) ((ushort*)Av)[(size_t)(r0 + r) * NCS + c] = f2bf(v);
            else     ((float*) Av)[(size_t)(r0 + r) * NCS + c] = v;
        }
    }
    #pragma unroll
    for (int ct = NCS / 16; ct < NCT; ++ct) {
        const int c = ct * 16 + m - NCS;
        #pragma unroll
        for (int r = 0; r < 4; ++r)
            Bt[(size_t)(r0 + r) * NCN + c] = f2bf(acc[ct][r]);
    }
}

// ---------------- aggregation ----------------
// wave per node: Hb[node] = relu(Abf[node] + mean(Bt[src])) as bf16. Unroll x8.
__global__ __launch_bounds__(256) void agg128_k(
    const int* __restrict__ row, const int* __restrict__ esrc,
    const ushort* __restrict__ Bt, const ushort* __restrict__ Abf, ushort* __restrict__ Hb)
{
    const int node = (blockIdx.x * 256 + threadIdx.x) >> 6;
    if (node >= NN) return;
    const int lane = threadIdx.x & 63;
    const int e0 = row[node];
    const int e1 = row[node + 1];
    const uint* B32 = (const uint*)Bt;
    float a0 = 0.f, a1 = 0.f;
    int e = e0;
    for (; e + 8 <= e1; e += 8) {
        int s[8];
        #pragma unroll
        for (int j = 0; j < 8; ++j) s[j] = esrc[e + j];
        uint w[8];
        #pragma unroll
        for (int j = 0; j < 8; ++j) w[j] = B32[(size_t)s[j] * 64 + lane];
        #pragma unroll
        for (int j = 0; j < 8; ++j) { a0 += bf_lo(w[j]); a1 += bf_hi(w[j]); }
    }
    for (; e + 2 <= e1; e += 2) {
        const uint w0 = B32[(size_t)esrc[e] * 64 + lane];
        const uint w1 = B32[(size_t)esrc[e + 1] * 64 + lane];
        a0 += bf_lo(w0) + bf_lo(w1);
        a1 += bf_hi(w0) + bf_hi(w1);
    }
    if (e < e1) {
        const uint w = B32[(size_t)esrc[e] * 64 + lane];
        a0 += bf_lo(w);
        a1 += bf_hi(w);
    }
    const float invd = (e1 > e0) ? 1.0f / (float)(e1 - e0) : 0.0f;
    const uint aw = ((const uint*)Abf)[(size_t)node * 64 + lane];
    float v0 = fmaxf(bf_lo(aw) + a0 * invd, 0.f);
    float v1 = fmaxf(bf_hi(aw) + a1 * invd, 0.f);
    ((uint*)Hb)[(size_t)node * 64 + lane] = (uint)f2bf(v0) | ((uint)f2bf(v1) << 16);
}

// layer 2: out[node] += mean(Bt64[src]) (fp32 in place, no relu). Unroll x8.
__global__ __launch_bounds__(256) void agg64_k(
    const int* __restrict__ row, const int* __restrict__ esrc,
    const ushort* __restrict__ Bt, float* __restrict__ out)
{
    const int node = (blockIdx.x * 256 + threadIdx.x) >> 6;
    if (node >= NN) return;
    const int lane = threadIdx.x & 63;
    const int e0 = row[node];
    const int e1 = row[node + 1];
    float a = 0.f;
    int e = e0;
    for (; e + 8 <= e1; e += 8) {
        int s[8];
        #pragma unroll
        for (int j = 0; j < 8; ++j) s[j] = esrc[e + j];
        ushort w[8];
        #pragma unroll
        for (int j = 0; j < 8; ++j) w[j] = Bt[(size_t)s[j] * 64 + lane];
        #pragma unroll
        for (int j = 0; j < 8; ++j) a += __uint_as_float((uint)w[j] << 16);
    }
    for (; e < e1; ++e)
        a += __uint_as_float((uint)Bt[(size_t)esrc[e] * 64 + lane] << 16);
    const float invd = (e1 > e0) ? 1.0f / (float)(e1 - e0) : 0.0f;
    out[(size_t)node * 64 + lane] += a * invd;
}

// ---------------- fp32 fallback path (small workspace) ----------------
__device__ inline float4 relu4f(float4 v) {
    v.x = fmaxf(v.x, 0.f); v.y = fmaxf(v.y, 0.f);
    v.z = fmaxf(v.z, 0.f); v.w = fmaxf(v.w, 0.f);
    return v;
}
template<int NCOL, bool RELU_IN, bool BIAS>
__global__ __launch_bounds__(256) void gemm_k(
    const float* in, const float* __restrict__ W,
    const float* __restrict__ bias, float* out)
{
    constexpr int K = 128;
    constexpr int QUADS = NCOL / 4;
    constexpr int G = 256 / QUADS;
    constexpr int RPT = 32 / G;
    __shared__ float Wlds[K * NCOL];
    {
        const float4* Wg = reinterpret_cast<const float4*>(W);
        float4* Wl = reinterpret_cast<float4*>(Wlds);
        #pragma unroll
        for (int i = 0; i < K * NCOL / 4 / 256; ++i)
            Wl[threadIdx.x + i * 256] = Wg[threadIdx.x + i * 256];
    }
    __syncthreads();
    const int tx = threadIdx.x % QUADS;
    const int ty = threadIdx.x / QUADS;
    const int row0 = blockIdx.x * 32;
    const float* rp[RPT];
    #pragma unroll
    for (int i = 0; i < RPT; ++i) rp[i] = in + (size_t)(row0 + ty + i * G) * K;
    float acc[RPT][4];
    #pragma unroll
    for (int i = 0; i < RPT; ++i) acc[i][0] = acc[i][1] = acc[i][2] = acc[i][3] = 0.f;
    #pragma unroll 2
    for (int kc = 0; kc < K; kc += 4) {
        float4 h4[RPT];
        #pragma unroll
        for (int i = 0; i < RPT; ++i) {
            h4[i] = *reinterpret_cast<const float4*>(rp[i] + kc);
            if (RELU_IN) h4[i] = relu4f(h4[i]);
        }
        #pragma unroll
        for (int kk = 0; kk < 4; ++kk) {
            const float4 w4 = *reinterpret_cast<const float4*>(&Wlds[(kc + kk) * NCOL + tx * 4]);
            #pragma unroll
            for (int i = 0; i < RPT; ++i) {
                const float hv = (&h4[i].x)[kk];
                acc[i][0] = fmaf(hv, w4.x, acc[i][0]);
                acc[i][1] = fmaf(hv, w4.y, acc[i][1]);
                acc[i][2] = fmaf(hv, w4.z, acc[i][2]);
                acc[i][3] = fmaf(hv, w4.w, acc[i][3]);
            }
        }
    }
    float4 b4 = make_float4(0.f, 0.f, 0.f, 0.f);
    if (BIAS) b4 = *reinterpret_cast<const float4*>(&bias[tx * 4]);
    #pragma unroll
    for (int i = 0; i < RPT; ++i) {
        const int r = row0 + ty + i * G;
        float4 o;
        o.x = acc[i][0] + b4.x; o.y = acc[i][1] + b4.y;
        o.z = acc[i][2] + b4.z; o.w = acc[i][3] + b4.w;
        *reinterpret_cast<float4*>(&out[(size_t)r * NCOL + tx * 4]) = o;
    }
}
__global__ void deg_k(const int* __restrict__ dst, float* __restrict__ deg, int E) {
    const int i = blockIdx.x * blockDim.x + threadIdx.x;
    if (i < E) atomicAdd(&deg[dst[i]], 1.0f);
}
__global__ void inv_k(float* deg, int n) {
    const int i = blockIdx.x * blockDim.x + threadIdx.x;
    if (i < n) deg[i] = 1.0f / fmaxf(deg[i], 1.0f);
}
__global__ __launch_bounds__(256) void scatter128_k(
    const int* __restrict__ src, const int* __restrict__ dst,
    const float* __restrict__ inv, const float* __restrict__ B, float* A, int E) {
    const int lane = threadIdx.x & 63;
    int w = (blockIdx.x * 256 + threadIdx.x) >> 6;
    const int nw = (gridDim.x * 256) >> 6;
    for (int e = w; e < E; e += nw) {
        const int s = src[e], d = dst[e];
        const float sc = inv[d];
        const float2 v = *reinterpret_cast<const float2*>(&B[(size_t)s * 128 + lane * 2]);
        atomicAdd(&A[(size_t)d * 128 + lane * 2    ], v.x * sc);
        atomicAdd(&A[(size_t)d * 128 + lane * 2 + 1], v.y * sc);
    }
}
__global__ __launch_bounds__(256) void scatter64_k(
    const int* __restrict__ src, const int* __restrict__ dst,
    const float* __restrict__ inv, const float* __restrict__ B, float* A, int E) {
    const int lane = threadIdx.x & 63;
    int w = (blockIdx.x * 256 + threadIdx.x) >> 6;
    const int nw = (gridDim.x * 256) >> 6;
    for (int e = w; e < E; e += nw) {
        const int s = src[e], d = dst[e];
        atomicAdd(&A[(size_t)d * 64 + lane], B[(size_t)s * 64 + lane] * inv[d]);
    }
}

extern "C" void kernel_launch(void* const* d_in, const int* in_sizes, int n_in,
                              void* d_out, int out_size, void* d_ws, size_t ws_size,
                              hipStream_t stream) {
    const float* x   = (const float*)d_in[0];
    const int*   src = (const int*)  d_in[1];
    const int*   dst = (const int*)  d_in[2];
    const float* ws0 = (const float*)d_in[3];
    const float* wn0 = (const float*)d_in[4];
    const float* b0  = (const float*)d_in[5];
    const float* ws1 = (const float*)d_in[6];
    const float* wn1 = (const float*)d_in[7];
    const float* b1  = (const float*)d_in[8];
    const float* ws2 = (const float*)d_in[9];
    const float* wn2 = (const float*)d_in[10];
    const float* b2  = (const float*)d_in[11];
    float* out = (float*)d_out;

    // workspace layout (byte offsets)
    const size_t O_BLK  = 4096;       // scan blocksums
    const size_t O_ROW  = 16384;      // (NN+1)*4
    const size_t O_WF0  = 417792;     // 65536
    const size_t O_WF1  = 483328;     // 65536
    const size_t O_WF2  = 548864;     // 32768
    const size_t O_ESRC = 581632;     // 6400000
    const size_t O_A    = 7364864;    // A bf16 25.6MB (pb + histG alias its front)
    const size_t O_PB   = O_A;                       // 6400000
    const size_t O_HIST = O_A + (8u << 20);          // 400384
    const size_t O_BT   = 58564864;   // 25600000
    const size_t O_HB   = 84164864;   // 25600000
    const size_t NEED   = 109764864;

    if (ws_size >= NEED) {
        int*    blks  = (int*)   ((char*)d_ws + O_BLK);
        int*    row   = (int*)   ((char*)d_ws + O_ROW);
        ushort* wf0   = (ushort*)((char*)d_ws + O_WF0);
        ushort* wf1   = (ushort*)((char*)d_ws + O_WF1);
        ushort* wf2   = (ushort*)((char*)d_ws + O_WF2);
        int*    esrc  = (int*)   ((char*)d_ws + O_ESRC);
        ushort* Abf   = (ushort*)((char*)d_ws + O_A);
        int*    pb    = (int*)   ((char*)d_ws + O_PB);
        int*    histG = (int*)   ((char*)d_ws + O_HIST);
        ushort* Bt    = (ushort*)((char*)d_ws + O_BT);
        ushort* Hb    = (ushort*)((char*)d_ws + O_HB);

        // deterministic bucketed CSR build
        phist_k<<<NBLKS, 256, 0, stream>>>(dst, histG);
        scan1_k<<<NSB, 256, 0, stream>>>(histG, blks);
        scan2_k<<<1, 128, 0, stream>>>(blks, NSB);
        scan3_k<<<NSB, 256, 0, stream>>>(histG, blks);
        pscatter_k<<<NBLKS, 256, 0, stream>>>(src, dst, histG, pb);
        bucket_place_k<<<NB, 256, 0, stream>>>(histG, pb, row, esrc);

        // all weight packs in one launch
        pack_all_k<<<40, 256, 0, stream>>>(ws0, wn0, wf0, ws1, wn1, wf1, ws2, wn2, wf2);

        const int GEMM_BLOCKS = (NN / 16 + 3) / 4;   // 1563
        const int AGG_BLOCKS  = (NN + 3) / 4;        // 25000

        // layer 0 (reads fp32 x directly; A bf16)
        gemm_mfma_k<128, 128, true,  true ><<<GEMM_BLOCKS, 256, 0, stream>>>(x,  wf0, b0, Abf, Bt);
        agg128_k<<<AGG_BLOCKS, 256, 0, stream>>>(row, esrc, Bt, Abf, Hb);
        // layer 1 (bf16 in, A bf16)
        gemm_mfma_k<128, 128, false, true ><<<GEMM_BLOCKS, 256, 0, stream>>>(Hb, wf1, b1, Abf, Bt);
        agg128_k<<<AGG_BLOCKS, 256, 0, stream>>>(row, esrc, Bt, Abf, Hb);
        // layer 2 (A fp32 straight to d_out; then in-place mean add)
        gemm_mfma_k<64, 64, false, false><<<GEMM_BLOCKS, 256, 0, stream>>>(Hb, wf2, b2, out, Bt);
        agg64_k<<<AGG_BLOCKS, 256, 0, stream>>>(row, esrc, Bt, out);
    } else {
        // fp32 atomic fallback
        float* inv = (float*)d_ws;
        float* H0  = (float*)((char*)d_ws + (1u << 20));
        float* Bf  = H0 + (size_t)NN * 128;
        const int GEMM_BLOCKS = NN / 32;
        const int SC_BLOCKS = 4096;
        hipMemsetAsync(inv, 0, NN * sizeof(float), stream);
        deg_k<<<(NE + 255) / 256, 256, 0, stream>>>(dst, inv, NE);
        inv_k<<<(NN + 255) / 256, 256, 0, stream>>>(inv, NN);
        gemm_k<128, false, false><<<GEMM_BLOCKS, 256, 0, stream>>>(x, wn0, nullptr, Bf);
        gemm_k<128, false, true ><<<GEMM_BLOCKS, 256, 0, stream>>>(x, ws0, b0, H0);
        scatter128_k<<<SC_BLOCKS, 256, 0, stream>>>(src, dst, inv, Bf, H0, NE);
        gemm_k<128, true, false><<<GEMM_BLOCKS, 256, 0, stream>>>(H0, wn1, nullptr, Bf);
        gemm_k<128, true, true ><<<GEMM_BLOCKS, 256, 0, stream>>>(H0, ws1, b1, H0);
        scatter128_k<<<SC_BLOCKS, 256, 0, stream>>>(src, dst, inv, Bf, H0, NE);
        gemm_k<64, true, false><<<GEMM_BLOCKS, 256, 0, stream>>>(H0, wn2, nullptr, Bf);
        gemm_k<64, true, true ><<<GEMM_BLOCKS, 256, 0, stream>>>(H0, ws2, b2, out);
        scatter64_k<<<SC_BLOCKS, 256, 0, stream>>>(src, dst, inv, Bf, out, NE);
    }
}

// Round 7
// 477.996 us; speedup vs baseline: 1.7699x; 1.0147x over previous
//
#include <hip/hip_runtime.h>

// GraphSAGE 3-layer forward. R7: wide-transaction gathers —
//   agg128: half-wave per edge, uint2 (8B) lane loads + shfl_xor(32) reduce
//   agg64:  two nodes per wave, uint (4B) lane loads
// plus fused phist+weight-pack launch and scan2 folded into scan3.
// Deterministic bucketed CSR build (R5). bf16 MFMA fused GEMMs (R6).

#define NN 100000
#define NE 1600000
#define BSH 7               // 128 dst-nodes per bucket
#define BND 128
#define NB  782             // ceil(100000/128)
#define NBLKS 128           // partition blocks for hist/scatter
#define EPB ((NE + NBLKS - 1) / NBLKS)   // 12500 edges per partition block
#define STOT (NB * NBLKS)   // 100096 scan entries
#define NSB ((STOT + 1023) / 1024)       // 98 scan blocks

typedef __attribute__((ext_vector_type(8))) short short8;
typedef __attribute__((ext_vector_type(4))) float f32x4;
typedef unsigned int uint;
typedef unsigned short ushort;

__device__ inline ushort f2bf(float f) {
    uint u = __float_as_uint(f);
    u += 0x7FFFu + ((u >> 16) & 1u);
    return (ushort)(u >> 16);
}
__device__ inline float bf_lo(uint w) { return __uint_as_float(w << 16); }
__device__ inline float bf_hi(uint w) { return __uint_as_float(w & 0xFFFF0000u); }

// ---------------- phase 1 + weight pack, one launch ----------------
// blocks [0,NBLKS): private per-block bucket histograms (LDS), stores to histG
// blocks [NBLKS, NBLKS+40): bf16 B-fragment-major weight pack for 3 layers
__global__ __launch_bounds__(256) void phist_pack_k(
    const int* __restrict__ dst, int* __restrict__ histG,
    const float* __restrict__ ws0, const float* __restrict__ wn0, ushort* __restrict__ wf0,
    const float* __restrict__ ws1, const float* __restrict__ wn1, ushort* __restrict__ wf1,
    const float* __restrict__ ws2, const float* __restrict__ wn2, ushort* __restrict__ wf2)
{
    __shared__ int h[NB];
    const int t = threadIdx.x;
    if (blockIdx.x < NBLKS) {
        for (int i = t; i < NB; i += 256) h[i] = 0;
        __syncthreads();
        const int blk = blockIdx.x;
        const int e0 = blk * EPB;
        const int e1 = min(e0 + EPB, NE);
        for (int e = e0 + t; e < e1; e += 256)
            atomicAdd(&h[dst[e] >> BSH], 1);
        __syncthreads();
        for (int i = t; i < NB; i += 256)
            histG[i * NBLKS + blk] = h[i];
        return;
    }
    // weight pack: frag f = ct*4+kt; lane l holds B[k=kt*32+(l>>4)*8+j][n=ct*16+(l&15)]
    const int b = blockIdx.x - NBLKS;
    const float *ws, *wn; ushort* wf; int ncs, idx;
    if (b < 16)      { ws = ws0; wn = wn0; wf = wf0; ncs = 128; idx = b * 256 + t; }
    else if (b < 32) { ws = ws1; wn = wn1; wf = wf1; ncs = 128; idx = (b - 16) * 256 + t; }
    else             { ws = ws2; wn = wn2; wf = wf2; ncs = 64;  idx = (b - 32) * 256 + t; }
    const int total = (2 * ncs / 16) * 4 * 64;
    if (idx >= total) return;
    const int l = idx & 63;
    const int f = idx >> 6;
    const int kt = f & 3;
    const int ct = f >> 2;
    const int n = ct * 16 + (l & 15);
    const int k0 = kt * 32 + (l >> 4) * 8;
    uint w[4];
    #pragma unroll
    for (int p = 0; p < 4; ++p) {
        const int k = k0 + p * 2;
        float v0, v1;
        if (n < ncs) { v0 = ws[k * ncs + n];         v1 = ws[(k + 1) * ncs + n]; }
        else         { v0 = wn[k * ncs + (n - ncs)]; v1 = wn[(k + 1) * ncs + (n - ncs)]; }
        w[p] = (uint)f2bf(v0) | ((uint)f2bf(v1) << 16);
    }
    uint4 o; o.x = w[0]; o.y = w[1]; o.z = w[2]; o.w = w[3];
    ((uint4*)wf)[idx] = o;
}

// ---------------- scan of histG[STOT] (2 kernels; scan2 folded into scan3) ----------------
__global__ __launch_bounds__(256) void scan1_k(int* __restrict__ data, int* __restrict__ blksum) {
    __shared__ int lds[256];
    const int t = threadIdx.x;
    const int base = blockIdx.x * 1024 + t * 4;
    int v[4];
    #pragma unroll
    for (int i = 0; i < 4; ++i) {
        const int idx = base + i;
        v[i] = (idx < STOT) ? data[idx] : 0;
    }
    const int s = v[0] + v[1] + v[2] + v[3];
    lds[t] = s;
    __syncthreads();
    #pragma unroll
    for (int off = 1; off < 256; off <<= 1) {
        const int cur = lds[t];
        const int y = (t >= off) ? lds[t - off] : 0;
        __syncthreads();
        lds[t] = cur + y;
        __syncthreads();
    }
    const int incl = lds[t];
    if (t == 255) blksum[blockIdx.x] = incl;
    int run = incl - s;
    #pragma unroll
    for (int i = 0; i < 4; ++i) {
        const int idx = base + i;
        if (idx < STOT) data[idx] = run;
        run += v[i];
    }
}

// scan3: every block scans the 98 block sums in LDS (cheap), adds its prefix
__global__ __launch_bounds__(256) void scan3_k(int* __restrict__ data, const int* __restrict__ blksum) {
    __shared__ int lds[128];
    const int t = threadIdx.x;
    if (t < 128) lds[t] = (t < NSB) ? blksum[t] : 0;
    __syncthreads();
    #pragma unroll
    for (int off = 1; off < 128; off <<= 1) {
        int nv = 0;
        if (t < 128) {
            nv = lds[t];
            if (t >= off) nv += lds[t - off];
        }
        __syncthreads();
        if (t < 128) lds[t] = nv;
        __syncthreads();
    }
    // exclusive prefix for this block = inclusive[b] - own
    const int add = (blockIdx.x == 0) ? 0 : lds[blockIdx.x - 1];
    const int base = blockIdx.x * 1024 + t * 4;
    #pragma unroll
    for (int i = 0; i < 4; ++i) {
        const int idx = base + i;
        if (idx < STOT) data[idx] += add;
    }
}

__global__ __launch_bounds__(256) void pscatter_k(const int* __restrict__ src,
                                                  const int* __restrict__ dst,
                                                  const int* __restrict__ histG,
                                                  int* __restrict__ pb) {
    __shared__ int wc[NB];
    const int t = threadIdx.x;
    const int blk = blockIdx.x;
    for (int i = t; i < NB; i += 256) wc[i] = histG[i * NBLKS + blk];
    __syncthreads();
    const int e0 = blk * EPB;
    const int e1 = min(e0 + EPB, NE);
    for (int e = e0 + t; e < e1; e += 256) {
        const int d = dst[e];
        const int pos = atomicAdd(&wc[d >> BSH], 1);
        pb[pos] = (src[e] << BSH) | (d & (BND - 1));
    }
}

__global__ __launch_bounds__(256) void bucket_place_k(const int* __restrict__ histG,
                                                      const int* __restrict__ pb,
                                                      int* __restrict__ row,
                                                      int* __restrict__ esrc) {
    __shared__ int cnt[BND], wc[BND], excl[BND], scan[BND];
    const int b = blockIdx.x;
    const int t = threadIdx.x;
    if (t < BND) { cnt[t] = 0; wc[t] = 0; }
    __syncthreads();
    const int s0 = histG[b * NBLKS];
    const int s1 = (b + 1 < NB) ? histG[(b + 1) * NBLKS] : NE;
    for (int e = s0 + t; e < s1; e += 256)
        atomicAdd(&cnt[pb[e] & (BND - 1)], 1);
    __syncthreads();
    if (t < BND) scan[t] = cnt[t];
    __syncthreads();
    for (int off = 1; off < BND; off <<= 1) {
        int nv = 0;
        if (t < BND) {
            nv = scan[t];
            if (t >= off) nv += scan[t - off];
        }
        __syncthreads();
        if (t < BND) scan[t] = nv;
        __syncthreads();
    }
    if (t < BND) {
        const int ex = scan[t] - cnt[t];
        excl[t] = ex;
        const int node = b * BND + t;
        if (node <= NN) row[node] = s0 + ex;
    }
    __syncthreads();
    for (int e = s0 + t; e < s1; e += 256) {
        const int p = pb[e];
        const int dl = p & (BND - 1);
        const int pos = s0 + excl[dl] + atomicAdd(&wc[dl], 1);
        esrc[pos] = p >> BSH;
    }
}

// ---------------- fused MFMA GEMM: [A | Bt] = H @ Wcat ----------------
template<int NCS, int NCN, bool XF32, bool ABF>
__global__ __launch_bounds__(256) void gemm_mfma_k(
    const void* __restrict__ Hv, const ushort* __restrict__ Wf,
    const float* __restrict__ bias, void* __restrict__ Av, ushort* __restrict__ Bt)
{
    constexpr int NCT = (NCS + NCN) / 16;
    const int g = (blockIdx.x * 256 + threadIdx.x) >> 6;
    if (g >= NN / 16) return;
    const int lane = threadIdx.x & 63;
    const int m = lane & 15;
    const int q = lane >> 4;

    short8 af[4];
    if (XF32) {
        const float* hp = (const float*)Hv + (size_t)(g * 16 + m) * 128;
        #pragma unroll
        for (int kt = 0; kt < 4; ++kt) {
            const float4 f0 = *(const float4*)(hp + kt * 32 + q * 8);
            const float4 f1 = *(const float4*)(hp + kt * 32 + q * 8 + 4);
            short8 v;
            v[0] = (short)f2bf(f0.x); v[1] = (short)f2bf(f0.y);
            v[2] = (short)f2bf(f0.z); v[3] = (short)f2bf(f0.w);
            v[4] = (short)f2bf(f1.x); v[5] = (short)f2bf(f1.y);
            v[6] = (short)f2bf(f1.z); v[7] = (short)f2bf(f1.w);
            af[kt] = v;
        }
    } else {
        const short8* hp = (const short8*)((const ushort*)Hv + (size_t)(g * 16 + m) * 128);
        #pragma unroll
        for (int kt = 0; kt < 4; ++kt) af[kt] = hp[kt * 4 + q];
    }

    f32x4 acc[NCT];
    #pragma unroll
    for (int i = 0; i < NCT; ++i) acc[i] = (f32x4){0.f, 0.f, 0.f, 0.f};

    const short8* wp = (const short8*)Wf;
    #pragma unroll
    for (int ct = 0; ct < NCT; ++ct) {
        #pragma unroll
        for (int kt = 0; kt < 4; ++kt) {
            const short8 bf = wp[(ct * 4 + kt) * 64 + lane];
            acc[ct] = __builtin_amdgcn_mfma_f32_16x16x32_bf16(af[kt], bf, acc[ct], 0, 0, 0);
        }
    }

    const int r0 = g * 16 + q * 4;
    #pragma unroll
    for (int ct = 0; ct < NCS / 16; ++ct) {
        const int c = ct * 16 + m;
        const float bv = bias[c];
        #pragma unroll
        for (int r = 0; r < 4; ++r) {
            const float v = acc[ct][r] + bv;
            if (ABF) ((ushort*)Av)[(size_t)(r0 + r) * NCS + c] = f2bf(v);
            else     ((float*) Av)[(size_t)(r0 + r) * NCS + c] = v;
        }
    }
    #pragma unroll
    for (int ct = NCS / 16; ct < NCT; ++ct) {
        const int c = ct * 16 + m - NCS;
        #pragma unroll
        for (int r = 0; r < 4; ++r)
            Bt[(size_t)(r0 + r) * NCN + c] = f2bf(acc[ct][r]);
    }
}

// ---------------- aggregation ----------------
// 128-wide: one wave per node, half-wave per edge (parity split), uint2 lane
// loads (8B). Cross-half combine via shfl_xor(32). Hb = relu(Abf + mean).
__global__ __launch_bounds__(256) void agg128_k(
    const int* __restrict__ row, const int* __restrict__ esrc,
    const ushort* __restrict__ Bt, const ushort* __restrict__ Abf, ushort* __restrict__ Hb)
{
    const int node = (blockIdx.x * 256 + threadIdx.x) >> 6;
    if (node >= NN) return;
    const int lane = threadIdx.x & 63;
    const int half = lane >> 5;
    const int ln = lane & 31;
    const int e0 = row[node];
    const int deg = row[node + 1] - e0;
    const int cnt = (deg + 1 - half) >> 1;      // edges of parity `half`
    const int base = e0 + half;
    const uint2* B64 = (const uint2*)Bt;        // row = 32 x uint2 (256B)

    float a0 = 0.f, a1 = 0.f, a2 = 0.f, a3 = 0.f;
    int k = 0;
    for (; k + 8 <= cnt; k += 8) {
        int s[8];
        #pragma unroll
        for (int j = 0; j < 8; ++j) s[j] = esrc[base + 2 * (k + j)];
        uint2 v[8];
        #pragma unroll
        for (int j = 0; j < 8; ++j) v[j] = B64[(size_t)s[j] * 32 + ln];
        #pragma unroll
        for (int j = 0; j < 8; ++j) {
            a0 += bf_lo(v[j].x); a1 += bf_hi(v[j].x);
            a2 += bf_lo(v[j].y); a3 += bf_hi(v[j].y);
        }
    }
    for (; k < cnt; ++k) {
        const int s = esrc[base + 2 * k];
        const uint2 v = B64[(size_t)s * 32 + ln];
        a0 += bf_lo(v.x); a1 += bf_hi(v.x);
        a2 += bf_lo(v.y); a3 += bf_hi(v.y);
    }
    // combine halves (feature ln*4.. of this node)
    a0 += __shfl_xor(a0, 32);
    a1 += __shfl_xor(a1, 32);
    a2 += __shfl_xor(a2, 32);
    a3 += __shfl_xor(a3, 32);

    if (half == 0) {
        const float invd = (deg > 0) ? 1.0f / (float)deg : 0.0f;
        const uint2 aw = ((const uint2*)Abf)[(size_t)node * 32 + ln];
        const float v0 = fmaxf(bf_lo(aw.x) + a0 * invd, 0.f);
        const float v1 = fmaxf(bf_hi(aw.x) + a1 * invd, 0.f);
        const float v2 = fmaxf(bf_lo(aw.y) + a2 * invd, 0.f);
        const float v3 = fmaxf(bf_hi(aw.y) + a3 * invd, 0.f);
        uint2 o;
        o.x = (uint)f2bf(v0) | ((uint)f2bf(v1) << 16);
        o.y = (uint)f2bf(v2) | ((uint)f2bf(v3) << 16);
        ((uint2*)Hb)[(size_t)node * 32 + ln] = o;
    }
}

// 64-wide: two nodes per wave (half-wave each), uint (4B) lane loads.
// out[node] += mean(Bt64[src]) fp32 in place, no relu.
__global__ __launch_bounds__(256) void agg64_k(
    const int* __restrict__ row, const int* __restrict__ esrc,
    const ushort* __restrict__ Bt, float* __restrict__ out)
{
    const int w = (blockIdx.x * 256 + threadIdx.x) >> 6;
    const int half = (threadIdx.x >> 5) & 1;
    const int ln = threadIdx.x & 31;
    const int node = w * 2 + half;
    if (node >= NN) return;
    const int e0 = row[node];
    const int e1 = row[node + 1];
    const uint* B32 = (const uint*)Bt;          // row = 32 x uint (128B)
    float a0 = 0.f, a1 = 0.f;
    int e = e0;
    for (; e + 8 <= e1; e += 8) {
        int s[8];
        #pragma unroll
        for (int j = 0; j < 8; ++j) s[j] = esrc[e + j];
        uint v[8];
        #pragma unroll
        for (int j = 0; j < 8; ++j) v[j] = B32[(size_t)s[j] * 32 + ln];
        #pragma unroll
        for (int j = 0; j < 8; ++j) { a0 += bf_lo(v[j]); a1 += bf_hi(v[j]); }
    }
    for (; e < e1; ++e) {
        const uint v = B32[(size_t)esrc[e] * 32 + ln];
        a0 += bf_lo(v); a1 += bf_hi(v);
    }
    const float invd = (e1 > e0) ? 1.0f / (float)(e1 - e0) : 0.0f;
    float2* op = (float2*)(out + (size_t)node * 64 + ln * 2);
    float2 o = *op;
    o.x += a0 * invd;
    o.y += a1 * invd;
    *op = o;
}

// ---------------- fp32 fallback path (small workspace) ----------------
__device__ inline float4 relu4f(float4 v) {
    v.x = fmaxf(v.x, 0.f); v.y = fmaxf(v.y, 0.f);
    v.z = fmaxf(v.z, 0.f); v.w = fmaxf(v.w, 0.f);
    return v;
}
template<int NCOL, bool RELU_IN, bool BIAS>
__global__ __launch_bounds__(256) void gemm_k(
    const float* in, const float* __restrict__ W,
    const float* __restrict__ bias, float* out)
{
    constexpr int K = 128;
    constexpr int QUADS = NCOL / 4;
    constexpr int G = 256 / QUADS;
    constexpr int RPT = 32 / G;
    __shared__ float Wlds[K * NCOL];
    {
        const float4* Wg = reinterpret_cast<const float4*>(W);
        float4* Wl = reinterpret_cast<float4*>(Wlds);
        #pragma unroll
        for (int i = 0; i < K * NCOL / 4 / 256; ++i)
            Wl[threadIdx.x + i * 256] = Wg[threadIdx.x + i * 256];
    }
    __syncthreads();
    const int tx = threadIdx.x % QUADS;
    const int ty = threadIdx.x / QUADS;
    const int row0 = blockIdx.x * 32;
    const float* rp[RPT];
    #pragma unroll
    for (int i = 0; i < RPT; ++i) rp[i] = in + (size_t)(row0 + ty + i * G) * K;
    float acc[RPT][4];
    #pragma unroll
    for (int i = 0; i < RPT; ++i) acc[i][0] = acc[i][1] = acc[i][2] = acc[i][3] = 0.f;
    #pragma unroll 2
    for (int kc = 0; kc < K; kc += 4) {
        float4 h4[RPT];
        #pragma unroll
        for (int i = 0; i < RPT; ++i) {
            h4[i] = *reinterpret_cast<const float4*>(rp[i] + kc);
            if (RELU_IN) h4[i] = relu4f(h4[i]);
        }
        #pragma unroll
        for (int kk = 0; kk < 4; ++kk) {
            const float4 w4 = *reinterpret_cast<const float4*>(&Wlds[(kc + kk) * NCOL + tx * 4]);
            #pragma unroll
            for (int i = 0; i < RPT; ++i) {
                const float hv = (&h4[i].x)[kk];
                acc[i][0] = fmaf(hv, w4.x, acc[i][0]);
                acc[i][1] = fmaf(hv, w4.y, acc[i][1]);
                acc[i][2] = fmaf(hv, w4.z, acc[i][2]);
                acc[i][3] = fmaf(hv, w4.w, acc[i][3]);
            }
        }
    }
    float4 b4 = make_float4(0.f, 0.f, 0.f, 0.f);
    if (BIAS) b4 = *reinterpret_cast<const float4*>(&bias[tx * 4]);
    #pragma unroll
    for (int i = 0; i < RPT; ++i) {
        const int r = row0 + ty + i * G;
        float4 o;
        o.x = acc[i][0] + b4.x; o.y = acc[i][1] + b4.y;
        o.z = acc[i][2] + b4.z; o.w = acc[i][3] + b4.w;
        *reinterpret_cast<float4*>(&out[(size_t)r * NCOL + tx * 4]) = o;
    }
}
__global__ void deg_k(const int* __restrict__ dst, float* __restrict__ deg, int E) {
    const int i = blockIdx.x * blockDim.x + threadIdx.x;
    if (i < E) atomicAdd(&deg[dst[i]], 1.0f);
}
__global__ void inv_k(float* deg, int n) {
    const int i = blockIdx.x * blockDim.x + threadIdx.x;
    if (i < n) deg[i] = 1.0f / fmaxf(deg[i], 1.0f);
}
__global__ __launch_bounds__(256) void scatter128_k(
    const int* __restrict__ src, const int* __restrict__ dst,
    const float* __restrict__ inv, const float* __restrict__ B, float* A, int E) {
    const int lane = threadIdx.x & 63;
    int w = (blockIdx.x * 256 + threadIdx.x) >> 6;
    const int nw = (gridDim.x * 256) >> 6;
    for (int e = w; e < E; e += nw) {
        const int s = src[e], d = dst[e];
        const float sc = inv[d];
        const float2 v = *reinterpret_cast<const float2*>(&B[(size_t)s * 128 + lane * 2]);
        atomicAdd(&A[(size_t)d * 128 + lane * 2    ], v.x * sc);
        atomicAdd(&A[(size_t)d * 128 + lane * 2 + 1], v.y * sc);
    }
}
__global__ __launch_bounds__(256) void scatter64_k(
    const int* __restrict__ src, const int* __restrict__ dst,
    const float* __restrict__ inv, const float* __restrict__ B, float* A, int E) {
    const int lane = threadIdx.x & 63;
    int w = (blockIdx.x * 256 + threadIdx.x) >> 6;
    const int nw = (gridDim.x * 256) >> 6;
    for (int e = w; e < E; e += nw) {
        const int s = src[e], d = dst[e];
        atomicAdd(&A[(size_t)d * 64 + lane], B[(size_t)s * 64 + lane] * inv[d]);
    }
}

extern "C" void kernel_launch(void* const* d_in, const int* in_sizes, int n_in,
                              void* d_out, int out_size, void* d_ws, size_t ws_size,
                              hipStream_t stream) {
    const float* x   = (const float*)d_in[0];
    const int*   src = (const int*)  d_in[1];
    const int*   dst = (const int*)  d_in[2];
    const float* ws0 = (const float*)d_in[3];
    const float* wn0 = (const float*)d_in[4];
    const float* b0  = (const float*)d_in[5];
    const float* ws1 = (const float*)d_in[6];
    const float* wn1 = (const float*)d_in[7];
    const float* b1  = (const float*)d_in[8];
    const float* ws2 = (const float*)d_in[9];
    const float* wn2 = (const float*)d_in[10];
    const float* b2  = (const float*)d_in[11];
    float* out = (float*)d_out;

    // workspace layout (byte offsets)
    const size_t O_BLK  = 4096;       // scan blocksums
    const size_t O_ROW  = 16384;      // (NN+1)*4
    const size_t O_WF0  = 417792;     // 65536
    const size_t O_WF1  = 483328;     // 65536
    const size_t O_WF2  = 548864;     // 32768
    const size_t O_ESRC = 581632;     // 6400000
    const size_t O_A    = 7364864;    // A bf16 25.6MB (pb + histG alias its front)
    const size_t O_PB   = O_A;                       // 6400000
    const size_t O_HIST = O_A + (8u << 20);          // 400384
    const size_t O_BT   = 58564864;   // 25600000
    const size_t O_HB   = 84164864;   // 25600000
    const size_t NEED   = 109764864;

    if (ws_size >= NEED) {
        int*    blks  = (int*)   ((char*)d_ws + O_BLK);
        int*    row   = (int*)   ((char*)d_ws + O_ROW);
        ushort* wf0   = (ushort*)((char*)d_ws + O_WF0);
        ushort* wf1   = (ushort*)((char*)d_ws + O_WF1);
        ushort* wf2   = (ushort*)((char*)d_ws + O_WF2);
        int*    esrc  = (int*)   ((char*)d_ws + O_ESRC);
        ushort* Abf   = (ushort*)((char*)d_ws + O_A);
        int*    pb    = (int*)   ((char*)d_ws + O_PB);
        int*    histG = (int*)   ((char*)d_ws + O_HIST);
        ushort* Bt    = (ushort*)((char*)d_ws + O_BT);
        ushort* Hb    = (ushort*)((char*)d_ws + O_HB);

        // CSR build + weight pack
        phist_pack_k<<<NBLKS + 40, 256, 0, stream>>>(dst, histG,
            ws0, wn0, wf0, ws1, wn1, wf1, ws2, wn2, wf2);
        scan1_k<<<NSB, 256, 0, stream>>>(histG, blks);
        scan3_k<<<NSB, 256, 0, stream>>>(histG, blks);
        pscatter_k<<<NBLKS, 256, 0, stream>>>(src, dst, histG, pb);
        bucket_place_k<<<NB, 256, 0, stream>>>(histG, pb, row, esrc);

        const int GEMM_BLOCKS = (NN / 16 + 3) / 4;   // 1563
        const int AGG_BLOCKS  = (NN + 3) / 4;        // 25000 (1 wave/node)
        const int AGG64_BLOCKS = (NN / 2 + 3) / 4;   // 12500 (2 nodes/wave)

        // layer 0 (reads fp32 x directly; A bf16)
        gemm_mfma_k<128, 128, true,  true ><<<GEMM_BLOCKS, 256, 0, stream>>>(x,  wf0, b0, Abf, Bt);
        agg128_k<<<AGG_BLOCKS, 256, 0, stream>>>(row, esrc, Bt, Abf, Hb);
        // layer 1 (bf16 in, A bf16)
        gemm_mfma_k<128, 128, false, true ><<<GEMM_BLOCKS, 256, 0, stream>>>(Hb, wf1, b1, Abf, Bt);
        agg128_k<<<AGG_BLOCKS, 256, 0, stream>>>(row, esrc, Bt, Abf, Hb);
        // layer 2 (A fp32 straight to d_out; then in-place mean add)
        gemm_mfma_k<64, 64, false, false><<<GEMM_BLOCKS, 256, 0, stream>>>(Hb, wf2, b2, out, Bt);
        agg64_k<<<AGG64_BLOCKS, 256, 0, stream>>>(row, esrc, Bt, out);
    } else {
        // fp32 atomic fallback
        float* inv = (float*)d_ws;
        float* H0  = (float*)((char*)d_ws + (1u << 20));
        float* Bf  = H0 + (size_t)NN * 128;
        const int GEMM_BLOCKS = NN / 32;
        const int SC_BLOCKS = 4096;
        hipMemsetAsync(inv, 0, NN * sizeof(float), stream);
        deg_k<<<(NE + 255) / 256, 256, 0, stream>>>(dst, inv, NE);
        inv_k<<<(NN + 255) / 256, 256, 0, stream>>>(inv, NN);
        gemm_k<128, false, false><<<GEMM_BLOCKS, 256, 0, stream>>>(x, wn0, nullptr, Bf);
        gemm_k<128, false, true ><<<GEMM_BLOCKS, 256, 0, stream>>>(x, ws0, b0, H0);
        scatter128_k<<<SC_BLOCKS, 256, 0, stream>>>(src, dst, inv, Bf, H0, NE);
        gemm_k<128, true, false><<<GEMM_BLOCKS, 256, 0, stream>>>(H0, wn1, nullptr, Bf);
        gemm_k<128, true, true ><<<GEMM_BLOCKS, 256, 0, stream>>>(H0, ws1, b1, H0);
        scatter128_k<<<SC_BLOCKS, 256, 0, stream>>>(src, dst, inv, Bf, H0, NE);
        gemm_k<64, true, false><<<GEMM_BLOCKS, 256, 0, stream>>>(H0, wn2, nullptr, Bf);
        gemm_k<64, true, true ><<<GEMM_BLOCKS, 256, 0, stream>>>(H0, ws2, b2, out);
        scatter64_k<<<SC_BLOCKS, 256, 0, stream>>>(src, dst, inv, Bf, out, NE);
    }
}

// Round 8
// 397.499 us; speedup vs baseline: 2.1283x; 1.2025x over previous
//
#include <hip/hip_runtime.h>

// GraphSAGE 3-layer forward. R8:
//   agg128: 2 nodes/wave (half-wave each, contiguous edges), uint2 8B lane loads
//   agg64:  4 nodes/wave (quarter-wave each), uint2 8B lane loads
//   CSR: 256 partition blocks (was 128); gemm0 fused into pscatter launch;
//   phist fused with weight pack. No workspace aliasing (NEED ~91MB).
// Per layer: [A | Bt] = H @ [Ws|Wn] (bf16 MFMA, fused self+neigh GEMM)
//            Hnext = relu(A + mean_{e:dst=d} Bt[src[e]]) stored bf16
//            (layer2: A fp32 straight to d_out, no relu)

#define NN 100000
#define NE 1600000
#define BSH 7               // 128 dst-nodes per bucket
#define BND 128
#define NB  782             // ceil(100000/128)
#define NBLKS 256           // partition blocks for hist/scatter
#define EPB ((NE + NBLKS - 1) / NBLKS)   // 6250 edges per partition block
#define STOT (NB * NBLKS)   // 200192 scan entries
#define NSB ((STOT + 1023) / 1024)       // 196 scan blocks
#define GEMM_BLOCKS 1563    // ceil((NN/16)/4)

typedef __attribute__((ext_vector_type(8))) short short8;
typedef __attribute__((ext_vector_type(4))) float f32x4;
typedef unsigned int uint;
typedef unsigned short ushort;

__device__ inline ushort f2bf(float f) {
    uint u = __float_as_uint(f);
    u += 0x7FFFu + ((u >> 16) & 1u);
    return (ushort)(u >> 16);
}
__device__ inline float bf_lo(uint w) { return __uint_as_float(w << 16); }
__device__ inline float bf_hi(uint w) { return __uint_as_float(w & 0xFFFF0000u); }

// ---------------- fused MFMA GEMM body (callable from fused launches) ----------------
template<int NCS, int NCN, bool XF32, bool ABF>
__device__ void gemm_body(int bid, int tid,
    const void* __restrict__ Hv, const ushort* __restrict__ Wf,
    const float* __restrict__ bias, void* __restrict__ Av, ushort* __restrict__ Bt)
{
    constexpr int NCT = (NCS + NCN) / 16;
    const int g = (bid * 256 + tid) >> 6;
    if (g >= NN / 16) return;
    const int lane = tid & 63;
    const int m = lane & 15;
    const int q = lane >> 4;

    short8 af[4];
    if (XF32) {
        const float* hp = (const float*)Hv + (size_t)(g * 16 + m) * 128;
        #pragma unroll
        for (int kt = 0; kt < 4; ++kt) {
            const float4 f0 = *(const float4*)(hp + kt * 32 + q * 8);
            const float4 f1 = *(const float4*)(hp + kt * 32 + q * 8 + 4);
            short8 v;
            v[0] = (short)f2bf(f0.x); v[1] = (short)f2bf(f0.y);
            v[2] = (short)f2bf(f0.z); v[3] = (short)f2bf(f0.w);
            v[4] = (short)f2bf(f1.x); v[5] = (short)f2bf(f1.y);
            v[6] = (short)f2bf(f1.z); v[7] = (short)f2bf(f1.w);
            af[kt] = v;
        }
    } else {
        const short8* hp = (const short8*)((const ushort*)Hv + (size_t)(g * 16 + m) * 128);
        #pragma unroll
        for (int kt = 0; kt < 4; ++kt) af[kt] = hp[kt * 4 + q];
    }

    f32x4 acc[NCT];
    #pragma unroll
    for (int i = 0; i < NCT; ++i) acc[i] = (f32x4){0.f, 0.f, 0.f, 0.f};

    const short8* wp = (const short8*)Wf;
    #pragma unroll
    for (int ct = 0; ct < NCT; ++ct) {
        #pragma unroll
        for (int kt = 0; kt < 4; ++kt) {
            const short8 bf = wp[(ct * 4 + kt) * 64 + lane];
            acc[ct] = __builtin_amdgcn_mfma_f32_16x16x32_bf16(af[kt], bf, acc[ct], 0, 0, 0);
        }
    }

    const int r0 = g * 16 + q * 4;
    #pragma unroll
    for (int ct = 0; ct < NCS / 16; ++ct) {
        const int c = ct * 16 + m;
        const float bv = bias[c];
        #pragma unroll
        for (int r = 0; r < 4; ++r) {
            const float v = acc[ct][r] + bv;
            if (ABF) ((ushort*)Av)[(size_t)(r0 + r) * NCS + c] = f2bf(v);
            else     ((float*) Av)[(size_t)(r0 + r) * NCS + c] = v;
        }
    }
    #pragma unroll
    for (int ct = NCS / 16; ct < NCT; ++ct) {
        const int c = ct * 16 + m - NCS;
        #pragma unroll
        for (int r = 0; r < 4; ++r)
            Bt[(size_t)(r0 + r) * NCN + c] = f2bf(acc[ct][r]);
    }
}

template<int NCS, int NCN, bool XF32, bool ABF>
__global__ __launch_bounds__(256) void gemm_mfma_k(
    const void* __restrict__ Hv, const ushort* __restrict__ Wf,
    const float* __restrict__ bias, void* __restrict__ Av, ushort* __restrict__ Bt)
{
    gemm_body<NCS, NCN, XF32, ABF>(blockIdx.x, threadIdx.x, Hv, Wf, bias, Av, Bt);
}

// ---------------- phase 1 + weight pack, one launch ----------------
__global__ __launch_bounds__(256) void phist_pack_k(
    const int* __restrict__ dst, int* __restrict__ histG,
    const float* __restrict__ ws0, const float* __restrict__ wn0, ushort* __restrict__ wf0,
    const float* __restrict__ ws1, const float* __restrict__ wn1, ushort* __restrict__ wf1,
    const float* __restrict__ ws2, const float* __restrict__ wn2, ushort* __restrict__ wf2)
{
    __shared__ int h[NB];
    const int t = threadIdx.x;
    if (blockIdx.x < NBLKS) {
        for (int i = t; i < NB; i += 256) h[i] = 0;
        __syncthreads();
        const int blk = blockIdx.x;
        const int e0 = blk * EPB;
        const int e1 = min(e0 + EPB, NE);
        for (int e = e0 + t; e < e1; e += 256)
            atomicAdd(&h[dst[e] >> BSH], 1);
        __syncthreads();
        for (int i = t; i < NB; i += 256)
            histG[i * NBLKS + blk] = h[i];
        return;
    }
    // weight pack: frag f = ct*4+kt; lane l holds B[k=kt*32+(l>>4)*8+j][n=ct*16+(l&15)]
    const int b = blockIdx.x - NBLKS;
    const float *ws, *wn; ushort* wf; int ncs, idx;
    if (b < 16)      { ws = ws0; wn = wn0; wf = wf0; ncs = 128; idx = b * 256 + t; }
    else if (b < 32) { ws = ws1; wn = wn1; wf = wf1; ncs = 128; idx = (b - 16) * 256 + t; }
    else             { ws = ws2; wn = wn2; wf = wf2; ncs = 64;  idx = (b - 32) * 256 + t; }
    const int total = (2 * ncs / 16) * 4 * 64;
    if (idx >= total) return;
    const int l = idx & 63;
    const int f = idx >> 6;
    const int kt = f & 3;
    const int ct = f >> 2;
    const int n = ct * 16 + (l & 15);
    const int k0 = kt * 32 + (l >> 4) * 8;
    uint w[4];
    #pragma unroll
    for (int p = 0; p < 4; ++p) {
        const int k = k0 + p * 2;
        float v0, v1;
        if (n < ncs) { v0 = ws[k * ncs + n];         v1 = ws[(k + 1) * ncs + n]; }
        else         { v0 = wn[k * ncs + (n - ncs)]; v1 = wn[(k + 1) * ncs + (n - ncs)]; }
        w[p] = (uint)f2bf(v0) | ((uint)f2bf(v1) << 16);
    }
    uint4 o; o.x = w[0]; o.y = w[1]; o.z = w[2]; o.w = w[3];
    ((uint4*)wf)[idx] = o;
}

// ---------------- scan of histG[STOT] ----------------
__global__ __launch_bounds__(256) void scan1_k(int* __restrict__ data, int* __restrict__ blksum) {
    __shared__ int lds[256];
    const int t = threadIdx.x;
    const int base = blockIdx.x * 1024 + t * 4;
    int v[4];
    #pragma unroll
    for (int i = 0; i < 4; ++i) {
        const int idx = base + i;
        v[i] = (idx < STOT) ? data[idx] : 0;
    }
    const int s = v[0] + v[1] + v[2] + v[3];
    lds[t] = s;
    __syncthreads();
    #pragma unroll
    for (int off = 1; off < 256; off <<= 1) {
        const int cur = lds[t];
        const int y = (t >= off) ? lds[t - off] : 0;
        __syncthreads();
        lds[t] = cur + y;
        __syncthreads();
    }
    const int incl = lds[t];
    if (t == 255) blksum[blockIdx.x] = incl;
    int run = incl - s;
    #pragma unroll
    for (int i = 0; i < 4; ++i) {
        const int idx = base + i;
        if (idx < STOT) data[idx] = run;
        run += v[i];
    }
}

// scan3: every block scans the 196 block sums in LDS, adds its exclusive prefix
__global__ __launch_bounds__(256) void scan3_k(int* __restrict__ data, const int* __restrict__ blksum) {
    __shared__ int lds[256];
    const int t = threadIdx.x;
    lds[t] = (t < NSB) ? blksum[t] : 0;
    __syncthreads();
    #pragma unroll
    for (int off = 1; off < 256; off <<= 1) {
        const int cur = lds[t];
        const int y = (t >= off) ? lds[t - off] : 0;
        __syncthreads();
        lds[t] = cur + y;
        __syncthreads();
    }
    const int add = (blockIdx.x == 0) ? 0 : lds[blockIdx.x - 1];
    const int base = blockIdx.x * 1024 + t * 4;
    #pragma unroll
    for (int i = 0; i < 4; ++i) {
        const int idx = base + i;
        if (idx < STOT) data[idx] += add;
    }
}

// Phase 3 (+ fused layer-0 GEMM): scatter packed pairs using scanned bases.
// blocks [0,NBLKS): pscatter; blocks [NBLKS, NBLKS+GEMM_BLOCKS): gemm0.
__global__ __launch_bounds__(256) void pscatter_gemm0_k(
    const int* __restrict__ src, const int* __restrict__ dst,
    const int* __restrict__ histG, int* __restrict__ pb,
    const float* __restrict__ x, const ushort* __restrict__ wf0,
    const float* __restrict__ b0, ushort* __restrict__ Abf, ushort* __restrict__ Bt)
{
    __shared__ int wc[NB];
    const int t = threadIdx.x;
    if (blockIdx.x < NBLKS) {
        const int blk = blockIdx.x;
        for (int i = t; i < NB; i += 256) wc[i] = histG[i * NBLKS + blk];
        __syncthreads();
        const int e0 = blk * EPB;
        const int e1 = min(e0 + EPB, NE);
        for (int e = e0 + t; e < e1; e += 256) {
            const int d = dst[e];
            const int pos = atomicAdd(&wc[d >> BSH], 1);
            pb[pos] = (src[e] << BSH) | (d & (BND - 1));
        }
        return;
    }
    gemm_body<128, 128, true, true>(blockIdx.x - NBLKS, t, x, wf0, b0, Abf, Bt);
}

// Phase 4: one block per bucket — local count, scan, place esrc, emit row[]
__global__ __launch_bounds__(256) void bucket_place_k(const int* __restrict__ histG,
                                                      const int* __restrict__ pb,
                                                      int* __restrict__ row,
                                                      int* __restrict__ esrc) {
    __shared__ int cnt[BND], wc[BND], excl[BND], scan[BND];
    const int b = blockIdx.x;
    const int t = threadIdx.x;
    if (t < BND) { cnt[t] = 0; wc[t] = 0; }
    __syncthreads();
    const int s0 = histG[b * NBLKS];
    const int s1 = (b + 1 < NB) ? histG[(b + 1) * NBLKS] : NE;
    for (int e = s0 + t; e < s1; e += 256)
        atomicAdd(&cnt[pb[e] & (BND - 1)], 1);
    __syncthreads();
    if (t < BND) scan[t] = cnt[t];
    __syncthreads();
    for (int off = 1; off < BND; off <<= 1) {
        int nv = 0;
        if (t < BND) {
            nv = scan[t];
            if (t >= off) nv += scan[t - off];
        }
        __syncthreads();
        if (t < BND) scan[t] = nv;
        __syncthreads();
    }
    if (t < BND) {
        const int ex = scan[t] - cnt[t];
        excl[t] = ex;
        const int node = b * BND + t;
        if (node <= NN) row[node] = s0 + ex;   // node==NN lands on row[NN]=NE
    }
    __syncthreads();
    for (int e = s0 + t; e < s1; e += 256) {
        const int p = pb[e];
        const int dl = p & (BND - 1);
        const int pos = s0 + excl[dl] + atomicAdd(&wc[dl], 1);
        esrc[pos] = p >> BSH;
    }
}

// ---------------- aggregation ----------------
// 128-wide: 2 nodes per wave (half-wave each, contiguous edges), uint2 loads.
__global__ __launch_bounds__(256) void agg128_k(
    const int* __restrict__ row, const int* __restrict__ esrc,
    const ushort* __restrict__ Bt, const ushort* __restrict__ Abf, ushort* __restrict__ Hb)
{
    const int w = (blockIdx.x * 256 + threadIdx.x) >> 6;
    const int half = (threadIdx.x >> 5) & 1;
    const int ln = threadIdx.x & 31;
    const int node = w * 2 + half;
    if (node >= NN) return;
    const int e0 = row[node];
    const int e1 = row[node + 1];
    const uint2* B = (const uint2*)Bt;          // row = 32 x uint2 (256B)
    float a0 = 0.f, a1 = 0.f, a2 = 0.f, a3 = 0.f;
    int e = e0;
    for (; e + 8 <= e1; e += 8) {
        int s[8];
        #pragma unroll
        for (int j = 0; j < 8; ++j) s[j] = esrc[e + j];
        uint2 v[8];
        #pragma unroll
        for (int j = 0; j < 8; ++j) v[j] = B[(size_t)s[j] * 32 + ln];
        #pragma unroll
        for (int j = 0; j < 8; ++j) {
            a0 += bf_lo(v[j].x); a1 += bf_hi(v[j].x);
            a2 += bf_lo(v[j].y); a3 += bf_hi(v[j].y);
        }
    }
    for (; e + 2 <= e1; e += 2) {
        const int s0 = esrc[e], s1 = esrc[e + 1];
        const uint2 v0 = B[(size_t)s0 * 32 + ln];
        const uint2 v1 = B[(size_t)s1 * 32 + ln];
        a0 += bf_lo(v0.x) + bf_lo(v1.x); a1 += bf_hi(v0.x) + bf_hi(v1.x);
        a2 += bf_lo(v0.y) + bf_lo(v1.y); a3 += bf_hi(v0.y) + bf_hi(v1.y);
    }
    if (e < e1) {
        const uint2 v = B[(size_t)esrc[e] * 32 + ln];
        a0 += bf_lo(v.x); a1 += bf_hi(v.x);
        a2 += bf_lo(v.y); a3 += bf_hi(v.y);
    }
    const int deg = e1 - e0;
    const float invd = (deg > 0) ? 1.0f / (float)deg : 0.0f;
    const uint2 aw = ((const uint2*)Abf)[(size_t)node * 32 + ln];
    const float v0 = fmaxf(bf_lo(aw.x) + a0 * invd, 0.f);
    const float v1 = fmaxf(bf_hi(aw.x) + a1 * invd, 0.f);
    const float v2 = fmaxf(bf_lo(aw.y) + a2 * invd, 0.f);
    const float v3 = fmaxf(bf_hi(aw.y) + a3 * invd, 0.f);
    uint2 o;
    o.x = (uint)f2bf(v0) | ((uint)f2bf(v1) << 16);
    o.y = (uint)f2bf(v2) | ((uint)f2bf(v3) << 16);
    ((uint2*)Hb)[(size_t)node * 32 + ln] = o;
}

// 64-wide: 4 nodes per wave (quarter-wave each), uint2 loads.
// out[node] += mean(Bt64[src]) fp32 in place, no relu.
__global__ __launch_bounds__(256) void agg64_k(
    const int* __restrict__ row, const int* __restrict__ esrc,
    const ushort* __restrict__ Bt, float* __restrict__ out)
{
    const int node = (blockIdx.x * 256 + threadIdx.x) >> 4;  // 16 lanes/node
    const int ln = threadIdx.x & 15;
    if (node >= NN) return;
    const int e0 = row[node];
    const int e1 = row[node + 1];
    const uint2* B = (const uint2*)Bt;          // row = 16 x uint2 (128B)
    float a0 = 0.f, a1 = 0.f, a2 = 0.f, a3 = 0.f;
    int e = e0;
    for (; e + 8 <= e1; e += 8) {
        int s[8];
        #pragma unroll
        for (int j = 0; j < 8; ++j) s[j] = esrc[e + j];
        uint2 v[8];
        #pragma unroll
        for (int j = 0; j < 8; ++j) v[j] = B[(size_t)s[j] * 16 + ln];
        #pragma unroll
        for (int j = 0; j < 8; ++j) {
            a0 += bf_lo(v[j].x); a1 += bf_hi(v[j].x);
            a2 += bf_lo(v[j].y); a3 += bf_hi(v[j].y);
        }
    }
    for (; e + 2 <= e1; e += 2) {
        const int s0 = esrc[e], s1 = esrc[e + 1];
        const uint2 v0 = B[(size_t)s0 * 16 + ln];
        const uint2 v1 = B[(size_t)s1 * 16 + ln];
        a0 += bf_lo(v0.x) + bf_lo(v1.x); a1 += bf_hi(v0.x) + bf_hi(v1.x);
        a2 += bf_lo(v0.y) + bf_lo(v1.y); a3 += bf_hi(v0.y) + bf_hi(v1.y);
    }
    if (e < e1) {
        const uint2 v = B[(size_t)esrc[e] * 16 + ln];
        a0 += bf_lo(v.x); a1 += bf_hi(v.x);
        a2 += bf_lo(v.y); a3 += bf_hi(v.y);
    }
    const int deg = e1 - e0;
    const float invd = (deg > 0) ? 1.0f / (float)deg : 0.0f;
    float4* op = (float4*)(out + (size_t)node * 64 + ln * 4);
    float4 o = *op;
    o.x += a0 * invd; o.y += a1 * invd;
    o.z += a2 * invd; o.w += a3 * invd;
    *op = o;
}

// ---------------- fp32 fallback path (small workspace) ----------------
__device__ inline float4 relu4f(float4 v) {
    v.x = fmaxf(v.x, 0.f); v.y = fmaxf(v.y, 0.f);
    v.z = fmaxf(v.z, 0.f); v.w = fmaxf(v.w, 0.f);
    return v;
}
template<int NCOL, bool RELU_IN, bool BIAS>
__global__ __launch_bounds__(256) void gemm_k(
    const float* in, const float* __restrict__ W,
    const float* __restrict__ bias, float* out)
{
    constexpr int K = 128;
    constexpr int QUADS = NCOL / 4;
    constexpr int G = 256 / QUADS;
    constexpr int RPT = 32 / G;
    __shared__ float Wlds[K * NCOL];
    {
        const float4* Wg = reinterpret_cast<const float4*>(W);
        float4* Wl = reinterpret_cast<float4*>(Wlds);
        #pragma unroll
        for (int i = 0; i < K * NCOL / 4 / 256; ++i)
            Wl[threadIdx.x + i * 256] = Wg[threadIdx.x + i * 256];
    }
    __syncthreads();
    const int tx = threadIdx.x % QUADS;
    const int ty = threadIdx.x / QUADS;
    const int row0 = blockIdx.x * 32;
    const float* rp[RPT];
    #pragma unroll
    for (int i = 0; i < RPT; ++i) rp[i] = in + (size_t)(row0 + ty + i * G) * K;
    float acc[RPT][4];
    #pragma unroll
    for (int i = 0; i < RPT; ++i) acc[i][0] = acc[i][1] = acc[i][2] = acc[i][3] = 0.f;
    #pragma unroll 2
    for (int kc = 0; kc < K; kc += 4) {
        float4 h4[RPT];
        #pragma unroll
        for (int i = 0; i < RPT; ++i) {
            h4[i] = *reinterpret_cast<const float4*>(rp[i] + kc);
            if (RELU_IN) h4[i] = relu4f(h4[i]);
        }
        #pragma unroll
        for (int kk = 0; kk < 4; ++kk) {
            const float4 w4 = *reinterpret_cast<const float4*>(&Wlds[(kc + kk) * NCOL + tx * 4]);
            #pragma unroll
            for (int i = 0; i < RPT; ++i) {
                const float hv = (&h4[i].x)[kk];
                acc[i][0] = fmaf(hv, w4.x, acc[i][0]);
                acc[i][1] = fmaf(hv, w4.y, acc[i][1]);
                acc[i][2] = fmaf(hv, w4.z, acc[i][2]);
                acc[i][3] = fmaf(hv, w4.w, acc[i][3]);
            }
        }
    }
    float4 b4 = make_float4(0.f, 0.f, 0.f, 0.f);
    if (BIAS) b4 = *reinterpret_cast<const float4*>(&bias[tx * 4]);
    #pragma unroll
    for (int i = 0; i < RPT; ++i) {
        const int r = row0 + ty + i * G;
        float4 o;
        o.x = acc[i][0] + b4.x; o.y = acc[i][1] + b4.y;
        o.z = acc[i][2] + b4.z; o.w = acc[i][3] + b4.w;
        *reinterpret_cast<float4*>(&out[(size_t)r * NCOL + tx * 4]) = o;
    }
}
__global__ void deg_k(const int* __restrict__ dst, float* __restrict__ deg, int E) {
    const int i = blockIdx.x * blockDim.x + threadIdx.x;
    if (i < E) atomicAdd(&deg[dst[i]], 1.0f);
}
__global__ void inv_k(float* deg, int n) {
    const int i = blockIdx.x * blockDim.x + threadIdx.x;
    if (i < n) deg[i] = 1.0f / fmaxf(deg[i], 1.0f);
}
__global__ __launch_bounds__(256) void scatter128_k(
    const int* __restrict__ src, const int* __restrict__ dst,
    const float* __restrict__ inv, const float* __restrict__ B, float* A, int E) {
    const int lane = threadIdx.x & 63;
    int w = (blockIdx.x * 256 + threadIdx.x) >> 6;
    const int nw = (gridDim.x * 256) >> 6;
    for (int e = w; e < E; e += nw) {
        const int s = src[e], d = dst[e];
        const float sc = inv[d];
        const float2 v = *reinterpret_cast<const float2*>(&B[(size_t)s * 128 + lane * 2]);
        atomicAdd(&A[(size_t)d * 128 + lane * 2    ], v.x * sc);
        atomicAdd(&A[(size_t)d * 128 + lane * 2 + 1], v.y * sc);
    }
}
__global__ __launch_bounds__(256) void scatter64_k(
    const int* __restrict__ src, const int* __restrict__ dst,
    const float* __restrict__ inv, const float* __restrict__ B, float* A, int E) {
    const int lane = threadIdx.x & 63;
    int w = (blockIdx.x * 256 + threadIdx.x) >> 6;
    const int nw = (gridDim.x * 256) >> 6;
    for (int e = w; e < E; e += nw) {
        const int s = src[e], d = dst[e];
        atomicAdd(&A[(size_t)d * 64 + lane], B[(size_t)s * 64 + lane] * inv[d]);
    }
}

extern "C" void kernel_launch(void* const* d_in, const int* in_sizes, int n_in,
                              void* d_out, int out_size, void* d_ws, size_t ws_size,
                              hipStream_t stream) {
    const float* x   = (const float*)d_in[0];
    const int*   src = (const int*)  d_in[1];
    const int*   dst = (const int*)  d_in[2];
    const float* ws0 = (const float*)d_in[3];
    const float* wn0 = (const float*)d_in[4];
    const float* b0  = (const float*)d_in[5];
    const float* ws1 = (const float*)d_in[6];
    const float* wn1 = (const float*)d_in[7];
    const float* b1  = (const float*)d_in[8];
    const float* ws2 = (const float*)d_in[9];
    const float* wn2 = (const float*)d_in[10];
    const float* b2  = (const float*)d_in[11];
    float* out = (float*)d_out;

    // workspace layout (byte offsets, no aliasing)
    const size_t O_BLK  = 4096;       // scan blocksums (784B)
    const size_t O_ROW  = 16384;      // (NN+1)*4
    const size_t O_WF0  = 417792;     // 65536
    const size_t O_WF1  = 483328;     // 65536
    const size_t O_WF2  = 548864;     // 32768
    const size_t O_ESRC = 581632;     // 6400000
    const size_t O_PB   = 6983680;    // 6400000
    const size_t O_HIST = 13385728;   // 800768
    const size_t O_A    = 14286848;   // 25600000 (bf16)
    const size_t O_BT   = 39890944;   // 25600000
    const size_t O_HB   = 65495040;   // 25600000
    const size_t NEED   = 91095040;

    if (ws_size >= NEED) {
        int*    blks  = (int*)   ((char*)d_ws + O_BLK);
        int*    row   = (int*)   ((char*)d_ws + O_ROW);
        ushort* wf0   = (ushort*)((char*)d_ws + O_WF0);
        ushort* wf1   = (ushort*)((char*)d_ws + O_WF1);
        ushort* wf2   = (ushort*)((char*)d_ws + O_WF2);
        int*    esrc  = (int*)   ((char*)d_ws + O_ESRC);
        int*    pb    = (int*)   ((char*)d_ws + O_PB);
        int*    histG = (int*)   ((char*)d_ws + O_HIST);
        ushort* Abf   = (ushort*)((char*)d_ws + O_A);
        ushort* Bt    = (ushort*)((char*)d_ws + O_BT);
        ushort* Hb    = (ushort*)((char*)d_ws + O_HB);

        // CSR build (+ weight pack fused, + gemm0 fused into pscatter)
        phist_pack_k<<<NBLKS + 40, 256, 0, stream>>>(dst, histG,
            ws0, wn0, wf0, ws1, wn1, wf1, ws2, wn2, wf2);
        scan1_k<<<NSB, 256, 0, stream>>>(histG, blks);
        scan3_k<<<NSB, 256, 0, stream>>>(histG, blks);
        pscatter_gemm0_k<<<NBLKS + GEMM_BLOCKS, 256, 0, stream>>>(
            src, dst, histG, pb, x, wf0, b0, Abf, Bt);
        bucket_place_k<<<NB, 256, 0, stream>>>(histG, pb, row, esrc);

        const int AGG128_BLOCKS = (NN / 2 + 3) / 4;   // 12500 (2 nodes/wave)
        const int AGG64_BLOCKS  = (NN + 63) / 64;     // 1563*... 16 lanes/node -> NN/16 thr... 
        // 16 lanes per node, 256 threads/block -> 16 nodes/block
        const int A64B = (NN + 15) / 16;              // 6250

        // layer 0 (gemm0 already done in fused launch)
        agg128_k<<<AGG128_BLOCKS, 256, 0, stream>>>(row, esrc, Bt, Abf, Hb);
        // layer 1
        gemm_mfma_k<128, 128, false, true ><<<GEMM_BLOCKS, 256, 0, stream>>>(Hb, wf1, b1, Abf, Bt);
        agg128_k<<<AGG128_BLOCKS, 256, 0, stream>>>(row, esrc, Bt, Abf, Hb);
        // layer 2 (A fp32 straight to d_out; then in-place mean add)
        gemm_mfma_k<64, 64, false, false><<<GEMM_BLOCKS, 256, 0, stream>>>(Hb, wf2, b2, out, Bt);
        agg64_k<<<A64B, 256, 0, stream>>>(row, esrc, Bt, out);
        (void)AGG64_BLOCKS;
    } else {
        // fp32 atomic fallback
        float* inv = (float*)d_ws;
        float* H0  = (float*)((char*)d_ws + (1u << 20));
        float* Bf  = H0 + (size_t)NN * 128;
        const int GB = NN / 32;
        const int SC_BLOCKS = 4096;
        hipMemsetAsync(inv, 0, NN * sizeof(float), stream);
        deg_k<<<(NE + 255) / 256, 256, 0, stream>>>(dst, inv, NE);
        inv_k<<<(NN + 255) / 256, 256, 0, stream>>>(inv, NN);
        gemm_k<128, false, false><<<GB, 256, 0, stream>>>(x, wn0, nullptr, Bf);
        gemm_k<128, false, true ><<<GB, 256, 0, stream>>>(x, ws0, b0, H0);
        scatter128_k<<<SC_BLOCKS, 256, 0, stream>>>(src, dst, inv, Bf, H0, NE);
        gemm_k<128, true, false><<<GB, 256, 0, stream>>>(H0, wn1, nullptr, Bf);
        gemm_k<128, true, true ><<<GB, 256, 0, stream>>>(H0, ws1, b1, H0);
        scatter128_k<<<SC_BLOCKS, 256, 0, stream>>>(src, dst, inv, Bf, H0, NE);
        gemm_k<64, true, false><<<GB, 256, 0, stream>>>(H0, wn2, nullptr, Bf);
        gemm_k<64, true, true ><<<GB, 256, 0, stream>>>(H0, ws2, b2, out);
        scatter64_k<<<SC_BLOCKS, 256, 0, stream>>>(src, dst, inv, Bf, out, NE);
    }
}